// Round 1
// baseline (2380.758 us; speedup 1.0000x reference)
//
#include <hip/hip_runtime.h>
#include <math.h>

#define B_ 4
#define T_ 1024
#define D_ 1024
#define H_ 4
#define DK_ 256
#define DV_ 512
#define KC_ 4

// ---------------- generic tiled SGEMM: C[M,N] = A[M,K] * B[K,N] (row-major) ----
#define BM 64
#define BN 64
#define BK 16

__global__ __launch_bounds__(256) void sgemm_kernel(const float* __restrict__ A,
                                                    const float* __restrict__ Bm,
                                                    float* __restrict__ C,
                                                    int M, int N, int K) {
    __shared__ float As[BK][BM + 1];
    __shared__ float Bs[BK][BN];
    int tid = threadIdx.x;
    int tx = tid & 15, ty = tid >> 4;
    int m0 = blockIdx.y * BM, n0 = blockIdx.x * BN;
    float acc[4][4] = {};
    for (int k0 = 0; k0 < K; k0 += BK) {
#pragma unroll
        for (int i = 0; i < 4; ++i) {
            int e = i * 256 + tid;
            int r = e >> 4, c = e & 15;
            As[c][r] = A[(size_t)(m0 + r) * K + k0 + c];
        }
#pragma unroll
        for (int i = 0; i < 4; ++i) {
            int e = i * 256 + tid;
            int r = e >> 6, c = e & 63;
            Bs[r][c] = Bm[(size_t)(k0 + r) * N + n0 + c];
        }
        __syncthreads();
#pragma unroll
        for (int kk = 0; kk < BK; ++kk) {
            float a[4], b[4];
#pragma unroll
            for (int i = 0; i < 4; ++i) a[i] = As[kk][ty * 4 + i];
#pragma unroll
            for (int j = 0; j < 4; ++j) b[j] = Bs[kk][tx * 4 + j];
#pragma unroll
            for (int i = 0; i < 4; ++i)
#pragma unroll
                for (int j = 0; j < 4; ++j)
                    acc[i][j] = fmaf(a[i], b[j], acc[i][j]);
        }
        __syncthreads();
    }
#pragma unroll
    for (int i = 0; i < 4; ++i)
#pragma unroll
        for (int j = 0; j < 4; ++j)
            C[(size_t)(m0 + ty * 4 + i) * N + n0 + tx * 4 + j] = acc[i][j];
}

// ---------------- beta = sigmoid(x@Wb), eg = exp(-exp(A_log)*softplus(x@Wa+dt_bias))
__global__ __launch_bounds__(256) void betag_kernel(const float* __restrict__ x,
                                                    const float* __restrict__ Wb,
                                                    const float* __restrict__ Wa,
                                                    const float* __restrict__ A_log,
                                                    const float* __restrict__ dt_bias,
                                                    float* __restrict__ beta,
                                                    float* __restrict__ eg) {
    int row = blockIdx.x;  // b*T + t
    int tid = threadIdx.x;
    const float* xr = x + (size_t)row * D_;
    float pb[H_] = {}, pa[H_] = {};
    for (int j = 0; j < D_ / 256; ++j) {
        int d = j * 256 + tid;
        float xv = xr[d];
#pragma unroll
        for (int h = 0; h < H_; ++h) {
            pb[h] = fmaf(xv, Wb[d * H_ + h], pb[h]);
            pa[h] = fmaf(xv, Wa[d * H_ + h], pa[h]);
        }
    }
#pragma unroll
    for (int h = 0; h < H_; ++h) {
        for (int off = 32; off; off >>= 1) {
            pb[h] += __shfl_down(pb[h], off);
            pa[h] += __shfl_down(pa[h], off);
        }
    }
    __shared__ float ws[4][2][H_];
    int lane = tid & 63, w = tid >> 6;
    if (lane == 0) {
#pragma unroll
        for (int h = 0; h < H_; ++h) {
            ws[w][0][h] = pb[h];
            ws[w][1][h] = pa[h];
        }
    }
    __syncthreads();
    if (tid < H_) {
        float db = ws[0][0][tid] + ws[1][0][tid] + ws[2][0][tid] + ws[3][0][tid];
        float da = ws[0][1][tid] + ws[1][1][tid] + ws[2][1][tid] + ws[3][1][tid];
        beta[(size_t)row * H_ + tid] = 1.f / (1.f + expf(-db));
        float z = da + dt_bias[tid];
        float sp = (z > 20.f) ? z : log1pf(expf(z));
        eg[(size_t)row * H_ + tid] = expf(-expf(A_log[tid]) * sp);
    }
}

// ---------------- causal depthwise conv + silu + l2norm (q, k) -----------------
__global__ __launch_bounds__(256) void convqk_kernel(const float* __restrict__ raw,
                                                     const float* __restrict__ w,
                                                     float* __restrict__ out) {
    int bt_h = blockIdx.x;          // (b*T+t)*H + h
    int h = bt_h & (H_ - 1);
    int row = bt_h >> 2;            // b*T + t
    int t = row & (T_ - 1);
    int c = threadIdx.x;            // 0..255 (DK)
    int C = h * DK_ + c;
    float acc = 0.f;
#pragma unroll
    for (int i = 0; i < KC_; ++i) {
        int tt = t - (KC_ - 1) + i;
        if (tt >= 0)
            acc = fmaf(raw[(size_t)(row - (KC_ - 1) + i) * (H_ * DK_) + C], w[C * KC_ + i], acc);
    }
    float s = acc / (1.f + expf(-acc));  // silu
    float ss = s * s;
    for (int off = 32; off; off >>= 1) ss += __shfl_down(ss, off);
    __shared__ float ws4[4];
    int lane = threadIdx.x & 63, wv = threadIdx.x >> 6;
    if (lane == 0) ws4[wv] = ss;
    __syncthreads();
    float tot = ws4[0] + ws4[1] + ws4[2] + ws4[3];
    float r = rsqrtf(tot + 1e-6f);
    out[(size_t)bt_h * DK_ + c] = s * r;
}

// ---------------- causal depthwise conv + silu (v) -----------------------------
__global__ __launch_bounds__(256) void convv_kernel(const float* __restrict__ raw,
                                                    const float* __restrict__ w,
                                                    float* __restrict__ out) {
    size_t idx = (size_t)blockIdx.x * 256 + threadIdx.x;  // over B*T*H*DV
    int C = idx & (H_ * DV_ - 1);
    int row = (int)(idx >> 11);
    int t = row & (T_ - 1);
    float acc = 0.f;
#pragma unroll
    for (int i = 0; i < KC_; ++i) {
        int tt = t - (KC_ - 1) + i;
        if (tt >= 0)
            acc = fmaf(raw[(size_t)(row - (KC_ - 1) + i) * (H_ * DV_) + C], w[C * KC_ + i], acc);
    }
    out[idx] = acc / (1.f + expf(-acc));
}

// ---------------- gated delta rule recurrence ----------------------------------
// grid: B*H*(DV/VC) blocks; block = 256 threads = 8 k-groups x 32 v-columns.
// Each thread owns S[k-range of 32][one v-column] in registers.
#define VC 32
__global__ __launch_bounds__(256) void recur_kernel(const float* __restrict__ q,
                                                    const float* __restrict__ k,
                                                    const float* __restrict__ v,
                                                    const float* __restrict__ eg,
                                                    const float* __restrict__ beta,
                                                    float* __restrict__ o) {
    int blk = blockIdx.x;
    int vc = blk & (DV_ / VC - 1);      // 0..15
    int bh = blk >> 4;                  // b*H + h
    int b = bh >> 2, h = bh & (H_ - 1);
    int tid = threadIdx.x;
    int kg = tid >> 5;                  // 0..7
    int vl = tid & 31;                  // 0..31
    int vcol = vc * VC + vl;

    float S[32];
#pragma unroll
    for (int i = 0; i < 32; ++i) S[i] = 0.f;

    __shared__ float kq[2 * DK_];
    __shared__ float vv[VC];
    __shared__ float red[8][VC];
    __shared__ float red2[8][VC];
    const float scale = 0.0625f;  // DK^-0.5

    for (int t = 0; t < T_; ++t) {
        size_t base = ((size_t)(b * T_ + t) * H_ + h);
        kq[tid] = k[base * DK_ + tid];
        kq[DK_ + tid] = q[base * DK_ + tid];
        if (tid < VC) vv[tid] = v[base * DV_ + vc * VC + tid];
        float egv = eg[base];
        float bev = beta[base];
        __syncthreads();

        const float* kt = &kq[kg * 32];
        const float* qt = &kq[DK_ + kg * 32];
        float partial = 0.f;
#pragma unroll
        for (int i = 0; i < 32; ++i) {
            S[i] *= egv;
            partial = fmaf(kt[i], S[i], partial);
        }
        red[kg][vl] = partial;
        __syncthreads();

        float kv = 0.f;
#pragma unroll
        for (int j = 0; j < 8; ++j) kv += red[j][vl];
        float delta = (vv[vl] - kv) * bev;

        float op = 0.f;
#pragma unroll
        for (int i = 0; i < 32; ++i) {
            S[i] = fmaf(kt[i], delta, S[i]);
            op = fmaf(qt[i], S[i], op);
        }
        red2[kg][vl] = op;
        __syncthreads();

        if (kg == 0) {
            float oo = 0.f;
#pragma unroll
            for (int j = 0; j < 8; ++j) oo += red2[j][vl];
            o[base * DV_ + vcol] = oo * scale;
        }
    }
}

// ---------------- gated RMSNorm: on = o*rsqrt(mean(o^2)+eps)*norm_w*silu(gate) --
__global__ __launch_bounds__(256) void gnorm_kernel(const float* __restrict__ o,
                                                    const float* __restrict__ gate,
                                                    const float* __restrict__ norm_w,
                                                    float* __restrict__ on) {
    int bth = blockIdx.x;  // (b*T+t)*H + h
    int tid = threadIdx.x;
    const float* orow = o + (size_t)bth * DV_;
    float v0 = orow[tid], v1 = orow[256 + tid];
    float ss = v0 * v0 + v1 * v1;
    for (int off = 32; off; off >>= 1) ss += __shfl_down(ss, off);
    __shared__ float ws4[4];
    int lane = tid & 63, wv = tid >> 6;
    if (lane == 0) ws4[wv] = ss;
    __syncthreads();
    float tot = ws4[0] + ws4[1] + ws4[2] + ws4[3];
    float r = rsqrtf(tot * (1.f / DV_) + 1e-5f);
    float g0 = gate[(size_t)bth * DV_ + tid];
    float g1 = gate[(size_t)bth * DV_ + 256 + tid];
    on[(size_t)bth * DV_ + tid] = v0 * r * norm_w[tid] * (g0 / (1.f + expf(-g0)));
    on[(size_t)bth * DV_ + 256 + tid] = v1 * r * norm_w[256 + tid] * (g1 / (1.f + expf(-g1)));
}

extern "C" void kernel_launch(void* const* d_in, const int* in_sizes, int n_in,
                              void* d_out, int out_size, void* d_ws, size_t ws_size,
                              hipStream_t stream) {
    const float* x = (const float*)d_in[0];
    const float* Wq = (const float*)d_in[1];
    const float* Wk = (const float*)d_in[2];
    const float* Wv = (const float*)d_in[3];
    const float* cqw = (const float*)d_in[4];
    const float* ckw = (const float*)d_in[5];
    const float* cvw = (const float*)d_in[6];
    const float* Wb = (const float*)d_in[7];
    const float* Wa = (const float*)d_in[8];
    const float* A_log = (const float*)d_in[9];
    const float* dt_bias = (const float*)d_in[10];
    const float* Wg = (const float*)d_in[11];
    const float* norm_w = (const float*)d_in[12];
    const float* Wo = (const float*)d_in[13];
    float* out = (float*)d_out;

    float* ws = (float*)d_ws;
    const size_t M4 = (size_t)4096 * 1024;  // 4M floats
    float* qraw = ws;            // [0, 4M)
    float* kraw = ws + M4;       // [4M, 8M)
    float* vraw = ws + 2 * M4;   // [8M, 16M)
    float* qn = ws + 4 * M4;     // [16M, 20M)
    float* kn = ws + 5 * M4;     // [20M, 24M)
    float* vn = ws + 6 * M4;     // [24M, 32M)
    float* o = ws;               // reuse [0, 8M)   (qraw/kraw free after conv)
    float* graw = ws + 2 * M4;   // reuse [8M, 16M) (vraw free after conv)
    float* on = ws + 4 * M4;     // reuse [16M, 24M) (qn/kn free after recurrence)
    float* eg = ws + 8 * M4;     // [32M, 32M+16K)
    float* beta = eg + (size_t)B_ * T_ * H_;

    dim3 blk(256);
    // projections
    sgemm_kernel<<<dim3(16, 64), blk, 0, stream>>>(x, Wq, qraw, 4096, 1024, 1024);
    sgemm_kernel<<<dim3(16, 64), blk, 0, stream>>>(x, Wk, kraw, 4096, 1024, 1024);
    sgemm_kernel<<<dim3(32, 64), blk, 0, stream>>>(x, Wv, vraw, 4096, 2048, 1024);
    betag_kernel<<<4096, blk, 0, stream>>>(x, Wb, Wa, A_log, dt_bias, beta, eg);
    // conv + silu (+ l2norm for q,k)
    convqk_kernel<<<16384, blk, 0, stream>>>(qraw, cqw, qn);
    convqk_kernel<<<16384, blk, 0, stream>>>(kraw, ckw, kn);
    convv_kernel<<<32768, blk, 0, stream>>>(vraw, cvw, vn);
    // gate projection (into freed vraw region)
    sgemm_kernel<<<dim3(32, 64), blk, 0, stream>>>(x, Wg, graw, 4096, 2048, 1024);
    // recurrence
    recur_kernel<<<256, blk, 0, stream>>>(qn, kn, vn, eg, beta, o);
    // gated RMSNorm
    gnorm_kernel<<<16384, blk, 0, stream>>>(o, graw, norm_w, on);
    // output projection
    sgemm_kernel<<<dim3(16, 64), blk, 0, stream>>>(on, Wo, out, 4096, 1024, 2048);
}

// Round 2
// 1923.807 us; speedup vs baseline: 1.2375x; 1.2375x over previous
//
#include <hip/hip_runtime.h>
#include <math.h>

#define B_ 4
#define T_ 1024
#define D_ 1024
#define H_ 4
#define DK_ 256
#define DV_ 512
#define KC_ 4

// ---------------- generic tiled SGEMM: C[M,N] = A[M,K] * B[K,N] (row-major) ----
#define BM 64
#define BN 64
#define BK 16

__global__ __launch_bounds__(256) void sgemm_kernel(const float* __restrict__ A,
                                                    const float* __restrict__ Bm,
                                                    float* __restrict__ C,
                                                    int M, int N, int K) {
    __shared__ float As[BK][BM + 1];
    __shared__ float Bs[BK][BN];
    int tid = threadIdx.x;
    int tx = tid & 15, ty = tid >> 4;
    int m0 = blockIdx.y * BM, n0 = blockIdx.x * BN;
    float acc[4][4] = {};
    for (int k0 = 0; k0 < K; k0 += BK) {
#pragma unroll
        for (int i = 0; i < 4; ++i) {
            int e = i * 256 + tid;
            int r = e >> 4, c = e & 15;
            As[c][r] = A[(size_t)(m0 + r) * K + k0 + c];
        }
#pragma unroll
        for (int i = 0; i < 4; ++i) {
            int e = i * 256 + tid;
            int r = e >> 6, c = e & 63;
            Bs[r][c] = Bm[(size_t)(k0 + r) * N + n0 + c];
        }
        __syncthreads();
#pragma unroll
        for (int kk = 0; kk < BK; ++kk) {
            float a[4], b[4];
#pragma unroll
            for (int i = 0; i < 4; ++i) a[i] = As[kk][ty * 4 + i];
#pragma unroll
            for (int j = 0; j < 4; ++j) b[j] = Bs[kk][tx * 4 + j];
#pragma unroll
            for (int i = 0; i < 4; ++i)
#pragma unroll
                for (int j = 0; j < 4; ++j)
                    acc[i][j] = fmaf(a[i], b[j], acc[i][j]);
        }
        __syncthreads();
    }
#pragma unroll
    for (int i = 0; i < 4; ++i)
#pragma unroll
        for (int j = 0; j < 4; ++j)
            C[(size_t)(m0 + ty * 4 + i) * N + n0 + tx * 4 + j] = acc[i][j];
}

// ---------------- beta = sigmoid(x@Wb), eg = exp(-exp(A_log)*softplus(x@Wa+dt_bias))
__global__ __launch_bounds__(256) void betag_kernel(const float* __restrict__ x,
                                                    const float* __restrict__ Wb,
                                                    const float* __restrict__ Wa,
                                                    const float* __restrict__ A_log,
                                                    const float* __restrict__ dt_bias,
                                                    float* __restrict__ beta,
                                                    float* __restrict__ eg) {
    int row = blockIdx.x;  // b*T + t
    int tid = threadIdx.x;
    const float* xr = x + (size_t)row * D_;
    float pb[H_] = {}, pa[H_] = {};
    for (int j = 0; j < D_ / 256; ++j) {
        int d = j * 256 + tid;
        float xv = xr[d];
#pragma unroll
        for (int h = 0; h < H_; ++h) {
            pb[h] = fmaf(xv, Wb[d * H_ + h], pb[h]);
            pa[h] = fmaf(xv, Wa[d * H_ + h], pa[h]);
        }
    }
#pragma unroll
    for (int h = 0; h < H_; ++h) {
        for (int off = 32; off; off >>= 1) {
            pb[h] += __shfl_down(pb[h], off);
            pa[h] += __shfl_down(pa[h], off);
        }
    }
    __shared__ float ws[4][2][H_];
    int lane = tid & 63, w = tid >> 6;
    if (lane == 0) {
#pragma unroll
        for (int h = 0; h < H_; ++h) {
            ws[w][0][h] = pb[h];
            ws[w][1][h] = pa[h];
        }
    }
    __syncthreads();
    if (tid < H_) {
        float db = ws[0][0][tid] + ws[1][0][tid] + ws[2][0][tid] + ws[3][0][tid];
        float da = ws[0][1][tid] + ws[1][1][tid] + ws[2][1][tid] + ws[3][1][tid];
        beta[(size_t)row * H_ + tid] = 1.f / (1.f + expf(-db));
        float z = da + dt_bias[tid];
        float sp = (z > 20.f) ? z : log1pf(expf(z));
        eg[(size_t)row * H_ + tid] = expf(-expf(A_log[tid]) * sp);
    }
}

// ---------------- causal depthwise conv + silu + l2norm (q, k) -----------------
__global__ __launch_bounds__(256) void convqk_kernel(const float* __restrict__ raw,
                                                     const float* __restrict__ w,
                                                     float* __restrict__ out) {
    int bt_h = blockIdx.x;          // (b*T+t)*H + h
    int h = bt_h & (H_ - 1);
    int row = bt_h >> 2;            // b*T + t
    int t = row & (T_ - 1);
    int c = threadIdx.x;            // 0..255 (DK)
    int C = h * DK_ + c;
    float acc = 0.f;
#pragma unroll
    for (int i = 0; i < KC_; ++i) {
        int tt = t - (KC_ - 1) + i;
        if (tt >= 0)
            acc = fmaf(raw[(size_t)(row - (KC_ - 1) + i) * (H_ * DK_) + C], w[C * KC_ + i], acc);
    }
    float s = acc / (1.f + expf(-acc));  // silu
    float ss = s * s;
    for (int off = 32; off; off >>= 1) ss += __shfl_down(ss, off);
    __shared__ float ws4[4];
    int lane = threadIdx.x & 63, wv = threadIdx.x >> 6;
    if (lane == 0) ws4[wv] = ss;
    __syncthreads();
    float tot = ws4[0] + ws4[1] + ws4[2] + ws4[3];
    float r = rsqrtf(tot + 1e-6f);
    out[(size_t)bt_h * DK_ + c] = s * r;
}

// ---------------- causal depthwise conv + silu (v) -----------------------------
__global__ __launch_bounds__(256) void convv_kernel(const float* __restrict__ raw,
                                                    const float* __restrict__ w,
                                                    float* __restrict__ out) {
    size_t idx = (size_t)blockIdx.x * 256 + threadIdx.x;  // over B*T*H*DV
    int C = idx & (H_ * DV_ - 1);
    int row = (int)(idx >> 11);
    int t = row & (T_ - 1);
    float acc = 0.f;
#pragma unroll
    for (int i = 0; i < KC_; ++i) {
        int tt = t - (KC_ - 1) + i;
        if (tt >= 0)
            acc = fmaf(raw[(size_t)(row - (KC_ - 1) + i) * (H_ * DV_) + C], w[C * KC_ + i], acc);
    }
    out[idx] = acc / (1.f + expf(-acc));
}

// ---------------- gated delta rule recurrence (pipelined, 2 barriers/step) -----
// grid: B*H*(DV/16) = 512 blocks (2 blocks/CU); block = 256 threads =
// 16 k-groups x 16 v-columns. Thread (kg,vl) owns S[k=kg*16..+15][vcol].
// Double-buffered LDS k/q/v; next-step data prefetched into registers.
__global__ __launch_bounds__(256) void recur_kernel(const float* __restrict__ q,
                                                    const float* __restrict__ k,
                                                    const float* __restrict__ v,
                                                    const float* __restrict__ eg,
                                                    const float* __restrict__ beta,
                                                    float* __restrict__ o) {
    int blk = blockIdx.x;
    int vc = blk & 31;              // 0..31 : which group of 16 v-cols
    int bh = blk >> 5;              // 0..15 : b*H + h
    int b = bh >> 2, h = bh & (H_ - 1);
    int tid = threadIdx.x;
    int kg = tid >> 4;              // 0..15
    int vl = tid & 15;              // 0..15

    float S[16];
#pragma unroll
    for (int i = 0; i < 16; ++i) S[i] = 0.f;

    __shared__ float kq[2][512];    // [buf][0..255]=k, [256..511]=q
    __shared__ float vv[2][16];
    __shared__ float red1[16][16];  // kv partials
    __shared__ float red2[16][16];  // o partials

    const float scale = 0.0625f;    // DK^-0.5
    size_t bTH = (size_t)b * T_ * H_ + h;  // base(t) = bTH + t*H_

    // prologue: t=0 -> LDS buf0
    {
        size_t bs = bTH;
        kq[0][tid] = k[bs * DK_ + tid];
        kq[0][256 + tid] = q[bs * DK_ + tid];
        if (tid < 16) vv[0][tid] = v[bs * DV_ + vc * 16 + tid];
    }
    float egc = eg[bTH], bec = beta[bTH];
    // prefetch t=1 into regs
    float kr = 0.f, qr = 0.f, vr = 0.f, egn = 0.f, ben = 0.f;
    {
        size_t bs = bTH + H_;
        kr = k[bs * DK_ + tid];
        qr = q[bs * DK_ + tid];
        if (tid < 16) vr = v[bs * DV_ + vc * 16 + tid];
        egn = eg[bs];
        ben = beta[bs];
    }
    __syncthreads();

    for (int t = 0; t < T_; ++t) {
        int buf = t & 1;
        // ---- phase 1: decay + kv partial
        float kt[16];
        const float4* kp = (const float4*)&kq[buf][kg * 16];
#pragma unroll
        for (int j = 0; j < 4; ++j) {
            float4 f = kp[j];
            kt[4 * j] = f.x; kt[4 * j + 1] = f.y; kt[4 * j + 2] = f.z; kt[4 * j + 3] = f.w;
        }
        float partial = 0.f;
#pragma unroll
        for (int i = 0; i < 16; ++i) {
            S[i] *= egc;
            partial = fmaf(kt[i], S[i], partial);
        }
        red1[kg][vl] = partial;
        __syncthreads();  // barrier A

        // ---- phase 2: kv reduce (redundant, broadcast reads), delta, S update, o partial
        float kv = 0.f;
#pragma unroll
        for (int j = 0; j < 16; ++j) kv += red1[j][vl];
        float delta = (vv[buf][vl] - kv) * bec;

        float qt[16];
        const float4* qp = (const float4*)&kq[buf][256 + kg * 16];
#pragma unroll
        for (int j = 0; j < 4; ++j) {
            float4 f = qp[j];
            qt[4 * j] = f.x; qt[4 * j + 1] = f.y; qt[4 * j + 2] = f.z; qt[4 * j + 3] = f.w;
        }
        float op = 0.f;
#pragma unroll
        for (int i = 0; i < 16; ++i) {
            S[i] = fmaf(kt[i], delta, S[i]);
            op = fmaf(qt[i], S[i], op);
        }
        red2[kg][vl] = op;

        // ---- stage t+1 regs -> LDS (other buffer), issue prefetch for t+2
        if (t + 1 < T_) {
            kq[buf ^ 1][tid] = kr;
            kq[buf ^ 1][256 + tid] = qr;
            if (tid < 16) vv[buf ^ 1][tid] = vr;
            egc = egn;
            bec = ben;
            if (t + 2 < T_) {
                size_t bs = bTH + (size_t)(t + 2) * H_;
                kr = k[bs * DK_ + tid];
                qr = q[bs * DK_ + tid];
                if (tid < 16) vr = v[bs * DV_ + vc * 16 + tid];
                egn = eg[bs];
                ben = beta[bs];
            }
        }
        __syncthreads();  // barrier B

        // ---- o reduce+store (overlaps next step's phase 1 on other waves)
        if (tid < 16) {
            float oo = 0.f;
#pragma unroll
            for (int j = 0; j < 16; ++j) oo += red2[j][tid];
            o[(bTH + (size_t)t * H_) * DV_ + vc * 16 + tid] = oo * scale;
        }
    }
}

// ---------------- gated RMSNorm: on = o*rsqrt(mean(o^2)+eps)*norm_w*silu(gate) --
__global__ __launch_bounds__(256) void gnorm_kernel(const float* __restrict__ o,
                                                    const float* __restrict__ gate,
                                                    const float* __restrict__ norm_w,
                                                    float* __restrict__ on) {
    int bth = blockIdx.x;  // (b*T+t)*H + h
    int tid = threadIdx.x;
    const float* orow = o + (size_t)bth * DV_;
    float v0 = orow[tid], v1 = orow[256 + tid];
    float ss = v0 * v0 + v1 * v1;
    for (int off = 32; off; off >>= 1) ss += __shfl_down(ss, off);
    __shared__ float ws4[4];
    int lane = tid & 63, wv = tid >> 6;
    if (lane == 0) ws4[wv] = ss;
    __syncthreads();
    float tot = ws4[0] + ws4[1] + ws4[2] + ws4[3];
    float r = rsqrtf(tot * (1.f / DV_) + 1e-5f);
    float g0 = gate[(size_t)bth * DV_ + tid];
    float g1 = gate[(size_t)bth * DV_ + 256 + tid];
    on[(size_t)bth * DV_ + tid] = v0 * r * norm_w[tid] * (g0 / (1.f + expf(-g0)));
    on[(size_t)bth * DV_ + 256 + tid] = v1 * r * norm_w[256 + tid] * (g1 / (1.f + expf(-g1)));
}

extern "C" void kernel_launch(void* const* d_in, const int* in_sizes, int n_in,
                              void* d_out, int out_size, void* d_ws, size_t ws_size,
                              hipStream_t stream) {
    const float* x = (const float*)d_in[0];
    const float* Wq = (const float*)d_in[1];
    const float* Wk = (const float*)d_in[2];
    const float* Wv = (const float*)d_in[3];
    const float* cqw = (const float*)d_in[4];
    const float* ckw = (const float*)d_in[5];
    const float* cvw = (const float*)d_in[6];
    const float* Wb = (const float*)d_in[7];
    const float* Wa = (const float*)d_in[8];
    const float* A_log = (const float*)d_in[9];
    const float* dt_bias = (const float*)d_in[10];
    const float* Wg = (const float*)d_in[11];
    const float* norm_w = (const float*)d_in[12];
    const float* Wo = (const float*)d_in[13];
    float* out = (float*)d_out;

    float* ws = (float*)d_ws;
    const size_t M4 = (size_t)4096 * 1024;  // 4M floats
    float* qraw = ws;            // [0, 4M)
    float* kraw = ws + M4;       // [4M, 8M)
    float* vraw = ws + 2 * M4;   // [8M, 16M)
    float* qn = ws + 4 * M4;     // [16M, 20M)
    float* kn = ws + 5 * M4;     // [20M, 24M)
    float* vn = ws + 6 * M4;     // [24M, 32M)
    float* o = ws;               // reuse [0, 8M)   (qraw/kraw free after conv)
    float* graw = ws + 2 * M4;   // reuse [8M, 16M) (vraw free after conv)
    float* on = ws + 4 * M4;     // reuse [16M, 24M) (qn/kn free after recurrence)
    float* eg = ws + 8 * M4;     // [32M, 32M+16K)
    float* beta = eg + (size_t)B_ * T_ * H_;

    dim3 blk(256);
    // projections
    sgemm_kernel<<<dim3(16, 64), blk, 0, stream>>>(x, Wq, qraw, 4096, 1024, 1024);
    sgemm_kernel<<<dim3(16, 64), blk, 0, stream>>>(x, Wk, kraw, 4096, 1024, 1024);
    sgemm_kernel<<<dim3(32, 64), blk, 0, stream>>>(x, Wv, vraw, 4096, 2048, 1024);
    betag_kernel<<<4096, blk, 0, stream>>>(x, Wb, Wa, A_log, dt_bias, beta, eg);
    // conv + silu (+ l2norm for q,k)
    convqk_kernel<<<16384, blk, 0, stream>>>(qraw, cqw, qn);
    convqk_kernel<<<16384, blk, 0, stream>>>(kraw, ckw, kn);
    convv_kernel<<<32768, blk, 0, stream>>>(vraw, cvw, vn);
    // gate projection (into freed vraw region)
    sgemm_kernel<<<dim3(32, 64), blk, 0, stream>>>(x, Wg, graw, 4096, 2048, 1024);
    // recurrence
    recur_kernel<<<512, blk, 0, stream>>>(qn, kn, vn, eg, beta, o);
    // gated RMSNorm
    gnorm_kernel<<<16384, blk, 0, stream>>>(o, graw, norm_w, on);
    // output projection
    sgemm_kernel<<<dim3(16, 64), blk, 0, stream>>>(on, Wo, out, 4096, 1024, 2048);
}

// Round 3
// 1340.837 us; speedup vs baseline: 1.7756x; 1.4348x over previous
//
#include <hip/hip_runtime.h>
#include <hip/hip_bf16.h>
#include <math.h>

#define B_ 4
#define T_ 1024
#define D_ 1024
#define H_ 4
#define DK_ 256
#define DV_ 512
#define KC_ 4

typedef __attribute__((ext_vector_type(4))) float floatx4;
typedef __attribute__((ext_vector_type(8))) short short8_t;

__device__ __forceinline__ unsigned short f2b(float f) {
    __hip_bfloat16 h = __float2bfloat16(f);
    return *(unsigned short*)&h;
}

// ---------------- f32 -> bf16 convert (vectorized, 4 elems/thread) -------------
__global__ __launch_bounds__(256) void tob16_kernel(const float* __restrict__ in,
                                                    unsigned short* __restrict__ out) {
    int i = blockIdx.x * 256 + threadIdx.x;
    float4 f = ((const float4*)in)[i];
    ushort4 u;
    u.x = f2b(f.x); u.y = f2b(f.y); u.z = f2b(f.z); u.w = f2b(f.w);
    ((ushort4*)out)[i] = u;
}

// ---------------- W[K,N] f32 -> Wt[N,K] bf16 (LDS-tiled transpose) -------------
__global__ __launch_bounds__(256) void transpose_bf16_kernel(const float* __restrict__ W,
                                                             unsigned short* __restrict__ Wt,
                                                             int K, int N) {
    __shared__ float Ls[32][33];
    int tx = threadIdx.x & 31, ty = threadIdx.x >> 5;  // ty 0..7
    int k0 = blockIdx.y * 32, n0 = blockIdx.x * 32;
#pragma unroll
    for (int i = 0; i < 4; ++i)
        Ls[ty * 4 + i][tx] = W[(size_t)(k0 + ty * 4 + i) * N + n0 + tx];
    __syncthreads();
#pragma unroll
    for (int i = 0; i < 4; ++i)
        Wt[(size_t)(n0 + ty * 4 + i) * K + k0 + tx] = f2b(Ls[tx][ty * 4 + i]);
}

// ---------------- bf16 MFMA GEMM: C[M,N]f32 = A[M,K]bf16 * Bt[N,K]bf16 ---------
// 128x128 tile, BK=32, 256 thr = 4 waves (2x2), 4x4 16x16x32 frags/wave.
__global__ __launch_bounds__(256) void gemm_bf16_kernel(const unsigned short* __restrict__ A,
                                                        const unsigned short* __restrict__ Bt,
                                                        float* __restrict__ C,
                                                        int M, int N, int K) {
    __shared__ unsigned short As[128 * 40];  // row stride 40 (pad 8): 2-way-free banks
    __shared__ unsigned short Bs[128 * 40];
    int tid = threadIdx.x;
    int m0 = blockIdx.y * 128, n0 = blockIdx.x * 128;
    int w = tid >> 6, lane = tid & 63;
    int wm = w >> 1, wn = w & 1;
    floatx4 acc[4][4] = {};

    int c0 = tid, c1 = 256 + tid;
    int r0 = c0 >> 2, col0 = (c0 & 3) * 8;
    int r1 = c1 >> 2, col1 = (c1 & 3) * 8;
    int koff = (lane >> 4) * 8;

    for (int k0 = 0; k0 < K; k0 += 32) {
        short8_t a0 = *(const short8_t*)&A[(size_t)(m0 + r0) * K + k0 + col0];
        short8_t a1 = *(const short8_t*)&A[(size_t)(m0 + r1) * K + k0 + col1];
        short8_t b0 = *(const short8_t*)&Bt[(size_t)(n0 + r0) * K + k0 + col0];
        short8_t b1 = *(const short8_t*)&Bt[(size_t)(n0 + r1) * K + k0 + col1];
        __syncthreads();  // previous iter's LDS reads done
        *(short8_t*)&As[r0 * 40 + col0] = a0;
        *(short8_t*)&As[r1 * 40 + col1] = a1;
        *(short8_t*)&Bs[r0 * 40 + col0] = b0;
        *(short8_t*)&Bs[r1 * 40 + col1] = b1;
        __syncthreads();
        short8_t af[4], bf[4];
#pragma unroll
        for (int f = 0; f < 4; ++f) {
            af[f] = *(const short8_t*)&As[(wm * 64 + f * 16 + (lane & 15)) * 40 + koff];
            bf[f] = *(const short8_t*)&Bs[(wn * 64 + f * 16 + (lane & 15)) * 40 + koff];
        }
#pragma unroll
        for (int i = 0; i < 4; ++i)
#pragma unroll
            for (int j = 0; j < 4; ++j)
                acc[i][j] = __builtin_amdgcn_mfma_f32_16x16x32_bf16(af[i], bf[j], acc[i][j], 0, 0, 0);
    }
#pragma unroll
    for (int i = 0; i < 4; ++i) {
        int row = m0 + wm * 64 + i * 16 + (lane >> 4) * 4;
#pragma unroll
        for (int j = 0; j < 4; ++j) {
            int col = n0 + wn * 64 + j * 16 + (lane & 15);
#pragma unroll
            for (int r = 0; r < 4; ++r)
                C[(size_t)(row + r) * N + col] = acc[i][j][r];
        }
    }
}

// ---------------- beta = sigmoid(x@Wb), eg = exp(-exp(A_log)*softplus(x@Wa+dt_bias))
__global__ __launch_bounds__(256) void betag_kernel(const float* __restrict__ x,
                                                    const float* __restrict__ Wb,
                                                    const float* __restrict__ Wa,
                                                    const float* __restrict__ A_log,
                                                    const float* __restrict__ dt_bias,
                                                    float* __restrict__ beta,
                                                    float* __restrict__ eg) {
    int row = blockIdx.x;  // b*T + t
    int tid = threadIdx.x;
    const float* xr = x + (size_t)row * D_;
    float pb[H_] = {}, pa[H_] = {};
    for (int j = 0; j < D_ / 256; ++j) {
        int d = j * 256 + tid;
        float xv = xr[d];
#pragma unroll
        for (int h = 0; h < H_; ++h) {
            pb[h] = fmaf(xv, Wb[d * H_ + h], pb[h]);
            pa[h] = fmaf(xv, Wa[d * H_ + h], pa[h]);
        }
    }
#pragma unroll
    for (int h = 0; h < H_; ++h) {
        for (int off = 32; off; off >>= 1) {
            pb[h] += __shfl_down(pb[h], off);
            pa[h] += __shfl_down(pa[h], off);
        }
    }
    __shared__ float ws[4][2][H_];
    int lane = tid & 63, w = tid >> 6;
    if (lane == 0) {
#pragma unroll
        for (int h = 0; h < H_; ++h) {
            ws[w][0][h] = pb[h];
            ws[w][1][h] = pa[h];
        }
    }
    __syncthreads();
    if (tid < H_) {
        float db = ws[0][0][tid] + ws[1][0][tid] + ws[2][0][tid] + ws[3][0][tid];
        float da = ws[0][1][tid] + ws[1][1][tid] + ws[2][1][tid] + ws[3][1][tid];
        beta[(size_t)row * H_ + tid] = 1.f / (1.f + expf(-db));
        float z = da + dt_bias[tid];
        float sp = (z > 20.f) ? z : log1pf(expf(z));
        eg[(size_t)row * H_ + tid] = expf(-expf(A_log[tid]) * sp);
    }
}

// ---------------- causal depthwise conv + silu + l2norm (q, k) -> bf16 ---------
__global__ __launch_bounds__(256) void convqk_kernel(const float* __restrict__ raw,
                                                     const float* __restrict__ w,
                                                     __hip_bfloat16* __restrict__ out) {
    int bt_h = blockIdx.x;          // (b*T+t)*H + h
    int h = bt_h & (H_ - 1);
    int row = bt_h >> 2;            // b*T + t
    int t = row & (T_ - 1);
    int c = threadIdx.x;            // 0..255 (DK)
    int C = h * DK_ + c;
    float acc = 0.f;
#pragma unroll
    for (int i = 0; i < KC_; ++i) {
        int tt = t - (KC_ - 1) + i;
        if (tt >= 0)
            acc = fmaf(raw[(size_t)(row - (KC_ - 1) + i) * (H_ * DK_) + C], w[C * KC_ + i], acc);
    }
    float s = acc / (1.f + expf(-acc));  // silu
    float ss = s * s;
    for (int off = 32; off; off >>= 1) ss += __shfl_down(ss, off);
    __shared__ float ws4[4];
    int lane = threadIdx.x & 63, wv = threadIdx.x >> 6;
    if (lane == 0) ws4[wv] = ss;
    __syncthreads();
    float tot = ws4[0] + ws4[1] + ws4[2] + ws4[3];
    float r = rsqrtf(tot + 1e-6f);
    out[(size_t)bt_h * DK_ + c] = __float2bfloat16(s * r);
}

// ---------------- causal depthwise conv + silu (v) -> bf16 ---------------------
__global__ __launch_bounds__(256) void convv_kernel(const float* __restrict__ raw,
                                                    const float* __restrict__ w,
                                                    __hip_bfloat16* __restrict__ out) {
    size_t idx = (size_t)blockIdx.x * 256 + threadIdx.x;  // over B*T*H*DV
    int C = idx & (H_ * DV_ - 1);
    int row = (int)(idx >> 11);
    int t = row & (T_ - 1);
    float acc = 0.f;
#pragma unroll
    for (int i = 0; i < KC_; ++i) {
        int tt = t - (KC_ - 1) + i;
        if (tt >= 0)
            acc = fmaf(raw[(size_t)(row - (KC_ - 1) + i) * (H_ * DV_) + C], w[C * KC_ + i], acc);
    }
    out[idx] = __float2bfloat16(acc / (1.f + expf(-acc)));
}

// ---------------- gated delta rule recurrence (pipelined, 2 barriers/step) -----
__global__ __launch_bounds__(256) void recur_kernel(const __hip_bfloat16* __restrict__ q,
                                                    const __hip_bfloat16* __restrict__ k,
                                                    const __hip_bfloat16* __restrict__ v,
                                                    const float* __restrict__ eg,
                                                    const float* __restrict__ beta,
                                                    float* __restrict__ o) {
    int blk = blockIdx.x;
    int vc = blk & 31;              // 0..31 : which group of 16 v-cols
    int bh = blk >> 5;              // 0..15 : b*H + h
    int b = bh >> 2, h = bh & (H_ - 1);
    int tid = threadIdx.x;
    int kg = tid >> 4;              // 0..15
    int vl = tid & 15;              // 0..15

    float S[16];
#pragma unroll
    for (int i = 0; i < 16; ++i) S[i] = 0.f;

    __shared__ float kq[2][512];    // [buf][0..255]=k, [256..511]=q
    __shared__ float vv[2][16];
    __shared__ float red1[16][16];  // kv partials
    __shared__ float red2[16][16];  // o partials

    const float scale = 0.0625f;    // DK^-0.5
    size_t bTH = (size_t)b * T_ * H_ + h;  // base(t) = bTH + t*H_

    {
        size_t bs = bTH;
        kq[0][tid] = __bfloat162float(k[bs * DK_ + tid]);
        kq[0][256 + tid] = __bfloat162float(q[bs * DK_ + tid]);
        if (tid < 16) vv[0][tid] = __bfloat162float(v[bs * DV_ + vc * 16 + tid]);
    }
    float egc = eg[bTH], bec = beta[bTH];
    float kr = 0.f, qr = 0.f, vr = 0.f, egn = 0.f, ben = 0.f;
    {
        size_t bs = bTH + H_;
        kr = __bfloat162float(k[bs * DK_ + tid]);
        qr = __bfloat162float(q[bs * DK_ + tid]);
        if (tid < 16) vr = __bfloat162float(v[bs * DV_ + vc * 16 + tid]);
        egn = eg[bs];
        ben = beta[bs];
    }
    __syncthreads();

    for (int t = 0; t < T_; ++t) {
        int buf = t & 1;
        float kt[16];
        const float4* kp = (const float4*)&kq[buf][kg * 16];
#pragma unroll
        for (int j = 0; j < 4; ++j) {
            float4 f = kp[j];
            kt[4 * j] = f.x; kt[4 * j + 1] = f.y; kt[4 * j + 2] = f.z; kt[4 * j + 3] = f.w;
        }
        float partial = 0.f;
#pragma unroll
        for (int i = 0; i < 16; ++i) {
            S[i] *= egc;
            partial = fmaf(kt[i], S[i], partial);
        }
        red1[kg][vl] = partial;
        __syncthreads();  // barrier A

        float kv = 0.f;
#pragma unroll
        for (int j = 0; j < 16; ++j) kv += red1[j][vl];
        float delta = (vv[buf][vl] - kv) * bec;

        float qt[16];
        const float4* qp = (const float4*)&kq[buf][256 + kg * 16];
#pragma unroll
        for (int j = 0; j < 4; ++j) {
            float4 f = qp[j];
            qt[4 * j] = f.x; qt[4 * j + 1] = f.y; qt[4 * j + 2] = f.z; qt[4 * j + 3] = f.w;
        }
        float op = 0.f;
#pragma unroll
        for (int i = 0; i < 16; ++i) {
            S[i] = fmaf(kt[i], delta, S[i]);
            op = fmaf(qt[i], S[i], op);
        }
        red2[kg][vl] = op;

        if (t + 1 < T_) {
            kq[buf ^ 1][tid] = kr;
            kq[buf ^ 1][256 + tid] = qr;
            if (tid < 16) vv[buf ^ 1][tid] = vr;
            egc = egn;
            bec = ben;
            if (t + 2 < T_) {
                size_t bs = bTH + (size_t)(t + 2) * H_;
                kr = __bfloat162float(k[bs * DK_ + tid]);
                qr = __bfloat162float(q[bs * DK_ + tid]);
                if (tid < 16) vr = __bfloat162float(v[bs * DV_ + vc * 16 + tid]);
                egn = eg[bs];
                ben = beta[bs];
            }
        }
        __syncthreads();  // barrier B

        if (tid < 16) {
            float oo = 0.f;
#pragma unroll
            for (int j = 0; j < 16; ++j) oo += red2[j][tid];
            o[(bTH + (size_t)t * H_) * DV_ + vc * 16 + tid] = oo * scale;
        }
    }
}

// ---------------- gated RMSNorm -> bf16 ----------------------------------------
__global__ __launch_bounds__(256) void gnorm_kernel(const float* __restrict__ o,
                                                    const float* __restrict__ gate,
                                                    const float* __restrict__ norm_w,
                                                    __hip_bfloat16* __restrict__ on) {
    int bth = blockIdx.x;  // (b*T+t)*H + h
    int tid = threadIdx.x;
    const float* orow = o + (size_t)bth * DV_;
    float v0 = orow[tid], v1 = orow[256 + tid];
    float ss = v0 * v0 + v1 * v1;
    for (int off = 32; off; off >>= 1) ss += __shfl_down(ss, off);
    __shared__ float ws4[4];
    int lane = tid & 63, wv = tid >> 6;
    if (lane == 0) ws4[wv] = ss;
    __syncthreads();
    float tot = ws4[0] + ws4[1] + ws4[2] + ws4[3];
    float r = rsqrtf(tot * (1.f / DV_) + 1e-5f);
    float g0 = gate[(size_t)bth * DV_ + tid];
    float g1 = gate[(size_t)bth * DV_ + 256 + tid];
    on[(size_t)bth * DV_ + tid] = __float2bfloat16(v0 * r * norm_w[tid] * (g0 / (1.f + expf(-g0))));
    on[(size_t)bth * DV_ + 256 + tid] = __float2bfloat16(v1 * r * norm_w[256 + tid] * (g1 / (1.f + expf(-g1))));
}

extern "C" void kernel_launch(void* const* d_in, const int* in_sizes, int n_in,
                              void* d_out, int out_size, void* d_ws, size_t ws_size,
                              hipStream_t stream) {
    const float* x = (const float*)d_in[0];
    const float* Wq = (const float*)d_in[1];
    const float* Wk = (const float*)d_in[2];
    const float* Wv = (const float*)d_in[3];
    const float* cqw = (const float*)d_in[4];
    const float* ckw = (const float*)d_in[5];
    const float* cvw = (const float*)d_in[6];
    const float* Wb = (const float*)d_in[7];
    const float* Wa = (const float*)d_in[8];
    const float* A_log = (const float*)d_in[9];
    const float* dt_bias = (const float*)d_in[10];
    const float* Wg = (const float*)d_in[11];
    const float* norm_w = (const float*)d_in[12];
    const float* Wo = (const float*)d_in[13];
    float* out = (float*)d_out;

    float* ws = (float*)d_ws;
    const size_t M1 = (size_t)1024 * 1024;  // 1M floats
    // fp32 regions (float offsets)
    float* qraw = ws;                 // [0, 4M)
    float* kraw = ws + 4 * M1;        // [4, 8M)
    float* vraw = ws + 8 * M1;        // [8, 16M)
    float* graw = ws + 8 * M1;        // [8, 16M) after convv consumes vraw
    float* o = ws;                    // [0, 8M) after convs consume qraw/kraw
    // bf16 regions (expressed as float offsets; each bf16 elem = 2B)
    __hip_bfloat16* qn = (__hip_bfloat16*)(ws + 16 * M1);   // 4M bf16 -> [16,18M)
    __hip_bfloat16* kn = (__hip_bfloat16*)(ws + 18 * M1);   // [18,20M)
    __hip_bfloat16* vn = (__hip_bfloat16*)(ws + 20 * M1);   // 8M bf16 -> [20,24M)
    __hip_bfloat16* onb = (__hip_bfloat16*)(ws + 16 * M1);  // reuse after recur
    float* eg = ws + 24 * M1;                               // 16K
    float* beta = eg + (size_t)B_ * T_ * H_;
    unsigned short* xb = (unsigned short*)(ws + 25 * M1);   // 4M bf16 -> [25,27M)
    unsigned short* WqT = (unsigned short*)(ws + 27 * M1);          // 1M bf16
    unsigned short* WkT = (unsigned short*)(ws + 27 * M1 + M1 / 2); // 1M bf16
    unsigned short* WvT = (unsigned short*)(ws + 28 * M1);          // 2M bf16
    unsigned short* WgT = (unsigned short*)(ws + 29 * M1);          // 2M bf16
    unsigned short* WoT = (unsigned short*)(ws + 30 * M1);          // 2M bf16

    dim3 blk(256);
    // bf16 conversion + weight transposes
    tob16_kernel<<<4096, blk, 0, stream>>>(x, xb);
    transpose_bf16_kernel<<<dim3(32, 32), blk, 0, stream>>>(Wq, WqT, 1024, 1024);
    transpose_bf16_kernel<<<dim3(32, 32), blk, 0, stream>>>(Wk, WkT, 1024, 1024);
    transpose_bf16_kernel<<<dim3(64, 32), blk, 0, stream>>>(Wv, WvT, 1024, 2048);
    transpose_bf16_kernel<<<dim3(64, 32), blk, 0, stream>>>(Wg, WgT, 1024, 2048);
    transpose_bf16_kernel<<<dim3(32, 64), blk, 0, stream>>>(Wo, WoT, 2048, 1024);
    // projections (bf16 MFMA)
    gemm_bf16_kernel<<<dim3(8, 32), blk, 0, stream>>>(xb, WqT, qraw, 4096, 1024, 1024);
    gemm_bf16_kernel<<<dim3(8, 32), blk, 0, stream>>>(xb, WkT, kraw, 4096, 1024, 1024);
    gemm_bf16_kernel<<<dim3(16, 32), blk, 0, stream>>>(xb, WvT, vraw, 4096, 2048, 1024);
    betag_kernel<<<4096, blk, 0, stream>>>(x, Wb, Wa, A_log, dt_bias, beta, eg);
    // conv + silu (+ l2norm for q,k) -> bf16
    convqk_kernel<<<16384, blk, 0, stream>>>(qraw, cqw, qn);
    convqk_kernel<<<16384, blk, 0, stream>>>(kraw, ckw, kn);
    convv_kernel<<<32768, blk, 0, stream>>>(vraw, cvw, vn);
    // gate projection (fp32 epilogue consumed by gnorm) into freed vraw region
    gemm_bf16_kernel<<<dim3(16, 32), blk, 0, stream>>>(xb, WgT, graw, 4096, 2048, 1024);
    // recurrence
    recur_kernel<<<512, blk, 0, stream>>>(qn, kn, vn, eg, beta, o);
    // gated RMSNorm -> bf16
    gnorm_kernel<<<16384, blk, 0, stream>>>(o, graw, norm_w, onb);
    // output projection
    gemm_bf16_kernel<<<dim3(8, 32), blk, 0, stream>>>((const unsigned short*)onb, WoT, out, 4096, 1024, 2048);
}

// Round 4
// 826.438 us; speedup vs baseline: 2.8807x; 1.6224x over previous
//
#include <hip/hip_runtime.h>
#include <hip/hip_bf16.h>
#include <math.h>

#define B_ 4
#define T_ 1024
#define D_ 1024
#define H_ 4
#define DK_ 256
#define DV_ 512
#define KC_ 4
#define CC 32   // chunk length

typedef __attribute__((ext_vector_type(4))) float floatx4;
typedef __attribute__((ext_vector_type(8))) short short8_t;

__device__ __forceinline__ unsigned short f2b(float f) {
    __hip_bfloat16 h = __float2bfloat16(f);
    return *(unsigned short*)&h;
}
__device__ __forceinline__ float b2f(unsigned short u) {
    unsigned int x = ((unsigned int)u) << 16;
    return *(float*)&x;
}

// ---------------- f32 -> bf16 convert (vectorized, 4 elems/thread) -------------
__global__ __launch_bounds__(256) void tob16_kernel(const float* __restrict__ in,
                                                    unsigned short* __restrict__ out) {
    int i = blockIdx.x * 256 + threadIdx.x;
    float4 f = ((const float4*)in)[i];
    ushort4 u;
    u.x = f2b(f.x); u.y = f2b(f.y); u.z = f2b(f.z); u.w = f2b(f.w);
    ((ushort4*)out)[i] = u;
}

// ---------------- W[K,N] f32 -> Wt[N,K] bf16 (LDS-tiled transpose) -------------
__global__ __launch_bounds__(256) void transpose_bf16_kernel(const float* __restrict__ W,
                                                             unsigned short* __restrict__ Wt,
                                                             int K, int N) {
    __shared__ float Ls[32][33];
    int tx = threadIdx.x & 31, ty = threadIdx.x >> 5;  // ty 0..7
    int k0 = blockIdx.y * 32, n0 = blockIdx.x * 32;
#pragma unroll
    for (int i = 0; i < 4; ++i)
        Ls[ty * 4 + i][tx] = W[(size_t)(k0 + ty * 4 + i) * N + n0 + tx];
    __syncthreads();
#pragma unroll
    for (int i = 0; i < 4; ++i)
        Wt[(size_t)(n0 + ty * 4 + i) * K + k0 + tx] = f2b(Ls[tx][ty * 4 + i]);
}

// ---------------- bf16 MFMA GEMM: C[M,N]f32 = A[M,K]bf16 * Bt[N,K]bf16 ---------
__global__ __launch_bounds__(256) void gemm_bf16_kernel(const unsigned short* __restrict__ A,
                                                        const unsigned short* __restrict__ Bt,
                                                        float* __restrict__ C,
                                                        int M, int N, int K) {
    __shared__ unsigned short As[128 * 40];
    __shared__ unsigned short Bs[128 * 40];
    int tid = threadIdx.x;
    int m0 = blockIdx.y * 128, n0 = blockIdx.x * 128;
    int w = tid >> 6, lane = tid & 63;
    int wm = w >> 1, wn = w & 1;
    floatx4 acc[4][4] = {};

    int c0 = tid, c1 = 256 + tid;
    int r0 = c0 >> 2, col0 = (c0 & 3) * 8;
    int r1 = c1 >> 2, col1 = (c1 & 3) * 8;
    int koff = (lane >> 4) * 8;

    for (int k0 = 0; k0 < K; k0 += 32) {
        short8_t a0 = *(const short8_t*)&A[(size_t)(m0 + r0) * K + k0 + col0];
        short8_t a1 = *(const short8_t*)&A[(size_t)(m0 + r1) * K + k0 + col1];
        short8_t b0 = *(const short8_t*)&Bt[(size_t)(n0 + r0) * K + k0 + col0];
        short8_t b1 = *(const short8_t*)&Bt[(size_t)(n0 + r1) * K + k0 + col1];
        __syncthreads();
        *(short8_t*)&As[r0 * 40 + col0] = a0;
        *(short8_t*)&As[r1 * 40 + col1] = a1;
        *(short8_t*)&Bs[r0 * 40 + col0] = b0;
        *(short8_t*)&Bs[r1 * 40 + col1] = b1;
        __syncthreads();
        short8_t af[4], bf[4];
#pragma unroll
        for (int f = 0; f < 4; ++f) {
            af[f] = *(const short8_t*)&As[(wm * 64 + f * 16 + (lane & 15)) * 40 + koff];
            bf[f] = *(const short8_t*)&Bs[(wn * 64 + f * 16 + (lane & 15)) * 40 + koff];
        }
#pragma unroll
        for (int i = 0; i < 4; ++i)
#pragma unroll
            for (int j = 0; j < 4; ++j)
                acc[i][j] = __builtin_amdgcn_mfma_f32_16x16x32_bf16(af[i], bf[j], acc[i][j], 0, 0, 0);
    }
#pragma unroll
    for (int i = 0; i < 4; ++i) {
        int row = m0 + wm * 64 + i * 16 + (lane >> 4) * 4;
#pragma unroll
        for (int j = 0; j < 4; ++j) {
            int col = n0 + wn * 64 + j * 16 + (lane & 15);
#pragma unroll
            for (int r = 0; r < 4; ++r)
                C[(size_t)(row + r) * N + col] = acc[i][j][r];
        }
    }
}

// ---------------- beta = sigmoid(x@Wb), g = -exp(A_log)*softplus(x@Wa+dt_bias) --
__global__ __launch_bounds__(256) void betag_kernel(const float* __restrict__ x,
                                                    const float* __restrict__ Wb,
                                                    const float* __restrict__ Wa,
                                                    const float* __restrict__ A_log,
                                                    const float* __restrict__ dt_bias,
                                                    float* __restrict__ beta,
                                                    float* __restrict__ g) {
    int row = blockIdx.x;  // b*T + t
    int tid = threadIdx.x;
    const float* xr = x + (size_t)row * D_;
    float pb[H_] = {}, pa[H_] = {};
    for (int j = 0; j < D_ / 256; ++j) {
        int d = j * 256 + tid;
        float xv = xr[d];
#pragma unroll
        for (int h = 0; h < H_; ++h) {
            pb[h] = fmaf(xv, Wb[d * H_ + h], pb[h]);
            pa[h] = fmaf(xv, Wa[d * H_ + h], pa[h]);
        }
    }
#pragma unroll
    for (int h = 0; h < H_; ++h) {
        for (int off = 32; off; off >>= 1) {
            pb[h] += __shfl_down(pb[h], off);
            pa[h] += __shfl_down(pa[h], off);
        }
    }
    __shared__ float ws[4][2][H_];
    int lane = tid & 63, w = tid >> 6;
    if (lane == 0) {
#pragma unroll
        for (int h = 0; h < H_; ++h) {
            ws[w][0][h] = pb[h];
            ws[w][1][h] = pa[h];
        }
    }
    __syncthreads();
    if (tid < H_) {
        float db = ws[0][0][tid] + ws[1][0][tid] + ws[2][0][tid] + ws[3][0][tid];
        float da = ws[0][1][tid] + ws[1][1][tid] + ws[2][1][tid] + ws[3][1][tid];
        beta[(size_t)row * H_ + tid] = 1.f / (1.f + expf(-db));
        float z = da + dt_bias[tid];
        float sp = (z > 20.f) ? z : log1pf(expf(z));
        g[(size_t)row * H_ + tid] = -expf(A_log[tid]) * sp;
    }
}

// ---------------- causal depthwise conv + silu + l2norm (q, k) -> bf16 ---------
__global__ __launch_bounds__(256) void convqk_kernel(const float* __restrict__ raw,
                                                     const float* __restrict__ w,
                                                     __hip_bfloat16* __restrict__ out) {
    int bt_h = blockIdx.x;
    int h = bt_h & (H_ - 1);
    int row = bt_h >> 2;
    int t = row & (T_ - 1);
    int c = threadIdx.x;
    int C = h * DK_ + c;
    float acc = 0.f;
#pragma unroll
    for (int i = 0; i < KC_; ++i) {
        int tt = t - (KC_ - 1) + i;
        if (tt >= 0)
            acc = fmaf(raw[(size_t)(row - (KC_ - 1) + i) * (H_ * DK_) + C], w[C * KC_ + i], acc);
    }
    float s = acc / (1.f + expf(-acc));
    float ss = s * s;
    for (int off = 32; off; off >>= 1) ss += __shfl_down(ss, off);
    __shared__ float ws4[4];
    int lane = threadIdx.x & 63, wv = threadIdx.x >> 6;
    if (lane == 0) ws4[wv] = ss;
    __syncthreads();
    float tot = ws4[0] + ws4[1] + ws4[2] + ws4[3];
    float r = rsqrtf(tot + 1e-6f);
    out[(size_t)bt_h * DK_ + c] = __float2bfloat16(s * r);
}

// ---------------- causal depthwise conv + silu (v) -> bf16 ---------------------
__global__ __launch_bounds__(256) void convv_kernel(const float* __restrict__ raw,
                                                    const float* __restrict__ w,
                                                    __hip_bfloat16* __restrict__ out) {
    size_t idx = (size_t)blockIdx.x * 256 + threadIdx.x;
    int C = idx & (H_ * DV_ - 1);
    int row = (int)(idx >> 11);
    int t = row & (T_ - 1);
    float acc = 0.f;
#pragma unroll
    for (int i = 0; i < KC_; ++i) {
        int tt = t - (KC_ - 1) + i;
        if (tt >= 0)
            acc = fmaf(raw[(size_t)(row - (KC_ - 1) + i) * (H_ * DV_) + C], w[C * KC_ + i], acc);
    }
    out[idx] = __float2bfloat16(acc / (1.f + expf(-acc)));
}

// ---------------- chunked gated delta rule ------------------------------------
// 128 blocks = 16 (b,h) x 8 v-slabs(64). 256 thr = 4 waves; wave w owns v-cols
// [w*16, w*16+16). Thread (hq=l>>4, vl=l&15): S_T[v=w*16+vl][k=32m+8hq+j] in
// S[m*8+j] (64 f32). Chunked form: u=(I+A)^-1 b; O = Lam*(Q S0) + (D.QK^T)U;
// S = Lam_C S0 + K'^T U. All matmuls 16x16x32 bf16 MFMA; S enters as hi/lo bf16.
__global__ __launch_bounds__(256, 1) void chunk_kernel(const __hip_bfloat16* __restrict__ qg,
                                                       const __hip_bfloat16* __restrict__ kg,
                                                       const __hip_bfloat16* __restrict__ vg,
                                                       const float* __restrict__ gl,
                                                       const float* __restrict__ betal,
                                                       float* __restrict__ o) {
    int blk = blockIdx.x;
    int vs = blk & 7;
    int bh = blk >> 3;
    int b = bh >> 2, h = bh & 3;
    int tid = threadIdx.x;
    int w = tid >> 6, l = tid & 63;
    int vl = l & 15, hq = l >> 4;
    int v0 = vs * 64;

    __shared__ unsigned short KQ[32][264];   // K or Q tile [ci][k], pad 8
    __shared__ unsigned short KT[256][40];   // decay-scaled K^T [k][ci]
    __shared__ unsigned short Vt[32][72];    // V tile [ci][v]
    __shared__ unsigned short Ab[32][40];    // A bf16
    __shared__ unsigned short Pt[32][40];    // P bf16
    __shared__ float Adiag[2][16][17];       // L = I + A diag blocks (f32)
    __shared__ float gcs[CC], lamb[CC], bets[CC], kdec[CC];
    __shared__ float Rs[4][32][17];          // per-wave scratch

    float S[64];
#pragma unroll
    for (int i = 0; i < 64; ++i) S[i] = 0.f;

    const unsigned short* qn = (const unsigned short*)qg;
    const unsigned short* kn = (const unsigned short*)kg;
    const unsigned short* vn = (const unsigned short*)vg;

    for (int nc = 0; nc < T_ / CC; ++nc) {
        int t0 = nc * CC;
        // ---- ph0: g/beta load + inclusive scan (lanes 0..31 of wave 0)
        if (tid < 32) {
            size_t base = ((size_t)(b * T_ + t0 + tid) * H_ + h);
            float gv = gl[base];
            float bv = betal[base];
            float x = gv;
#pragma unroll
            for (int off = 1; off < 32; off <<= 1) {
                float y = __shfl_up(x, off);
                if (tid >= off) x += y;
            }
            gcs[tid] = x;
            lamb[tid] = expf(x);
            bets[tid] = bv;
            float tot = __shfl(x, 31);
            kdec[tid] = expf(tot - x);
        }
        __syncthreads();
        // ---- ph1: stage K -> KQ, KT(scaled), V -> Vt
        {
            int r = tid >> 3, c8 = (tid & 7) * 32;
            size_t gbase = ((size_t)(b * T_ + t0 + r) * H_ + h) * DK_;
            float kd = kdec[r];
#pragma unroll
            for (int ii = 0; ii < 4; ++ii) {
                short8_t kv8 = *(const short8_t*)&kn[gbase + c8 + ii * 8];
                *(short8_t*)&KQ[r][c8 + ii * 8] = kv8;
#pragma unroll
                for (int jj = 0; jj < 8; ++jj)
                    KT[c8 + ii * 8 + jj][r] = f2b(b2f((unsigned short)kv8[jj]) * kd);
            }
            size_t vb = ((size_t)(b * T_ + t0 + r) * H_ + h) * DV_ + v0 + (tid & 7) * 8;
            *(short8_t*)&Vt[r][(tid & 7) * 8] = *(const short8_t*)&vn[vb];
        }
        __syncthreads();
        // ---- ph2: waves 0-2: A = beta*D.(KK^T) strict-lower; P = D'.(QK^T)
        if (w < 3) {
            int mt = (w == 0) ? 0 : 1;
            int nt = (w == 2) ? 1 : 0;
            floatx4 acc = {};
#pragma unroll
            for (int k0 = 0; k0 < 8; ++k0) {
                short8_t a = *(const short8_t*)&KQ[mt * 16 + vl][k0 * 32 + hq * 8];
                short8_t bb = *(const short8_t*)&KQ[nt * 16 + vl][k0 * 32 + hq * 8];
                acc = __builtin_amdgcn_mfma_f32_16x16x32_bf16(a, bb, acc, 0, 0, 0);
            }
#pragma unroll
            for (int r = 0; r < 4; ++r) {
                int i = mt * 16 + 4 * hq + r, j = nt * 16 + vl;
                float val = (j < i) ? bets[i] * expf(gcs[i] - gcs[j]) * acc[r] : 0.f;
                Ab[i][j] = f2b(val);
                if (mt == nt) Adiag[mt][i - mt * 16][j - nt * 16] = (j < i) ? val : ((j == i) ? 1.f : 0.f);
            }
            floatx4 accp = {};
#pragma unroll
            for (int k0 = 0; k0 < 8; ++k0) {
                size_t qrow = ((size_t)(b * T_ + t0 + mt * 16 + vl) * H_ + h) * DK_ + k0 * 32 + hq * 8;
                short8_t a = *(const short8_t*)&qn[qrow];
                short8_t bb = *(const short8_t*)&KQ[nt * 16 + vl][k0 * 32 + hq * 8];
                accp = __builtin_amdgcn_mfma_f32_16x16x32_bf16(a, bb, accp, 0, 0, 0);
            }
#pragma unroll
            for (int r = 0; r < 4; ++r) {
                int i = mt * 16 + 4 * hq + r, j = nt * 16 + vl;
                Pt[i][j] = f2b((j <= i) ? expf(gcs[i] - gcs[j]) * accp[r] : 0.f);
            }
        } else {
            // zero Pt upper-right block [0..15][16..31]
#pragma unroll
            for (int ii = 0; ii < 4; ++ii)
                Pt[l >> 2][16 + (l & 3) * 4 + ii] = 0;
        }
        // ---- ph3: M2 = K @ S0 (hi+lo) -> b -> Rs
        {
            floatx4 bacc0 = {}, bacc1 = {};
#pragma unroll
            for (int k0 = 0; k0 < 8; ++k0) {
                short8_t bhi, blo;
#pragma unroll
                for (int j = 0; j < 8; ++j) {
                    float sv = S[k0 * 8 + j];
                    unsigned short hh = f2b(sv);
                    bhi[j] = (short)hh;
                    blo[j] = (short)f2b(sv - b2f(hh));
                }
                short8_t a0 = *(const short8_t*)&KQ[vl][k0 * 32 + hq * 8];
                short8_t a1 = *(const short8_t*)&KQ[16 + vl][k0 * 32 + hq * 8];
                bacc0 = __builtin_amdgcn_mfma_f32_16x16x32_bf16(a0, bhi, bacc0, 0, 0, 0);
                bacc0 = __builtin_amdgcn_mfma_f32_16x16x32_bf16(a0, blo, bacc0, 0, 0, 0);
                bacc1 = __builtin_amdgcn_mfma_f32_16x16x32_bf16(a1, bhi, bacc1, 0, 0, 0);
                bacc1 = __builtin_amdgcn_mfma_f32_16x16x32_bf16(a1, blo, bacc1, 0, 0, 0);
            }
#pragma unroll
            for (int mt = 0; mt < 2; ++mt)
#pragma unroll
                for (int r = 0; r < 4; ++r) {
                    int ci = mt * 16 + 4 * hq + r;
                    float vv = b2f(Vt[ci][w * 16 + vl]);
                    float acc = mt ? bacc1[r] : bacc0[r];
                    Rs[w][ci][vl] = bets[ci] * (vv - lamb[ci] * acc);
                }
        }
        __syncthreads();
        // ---- ph4: stage Q -> KQ
        {
            int r = tid >> 3, c8 = (tid & 7) * 32;
            size_t gbase = ((size_t)(b * T_ + t0 + r) * H_ + h) * DK_;
#pragma unroll
            for (int ii = 0; ii < 4; ++ii)
                *(short8_t*)&KQ[r][c8 + ii * 8] = *(const short8_t*)&qn[gbase + c8 + ii * 8];
        }
        __syncthreads();
        // ---- ph5: M3 = Q @ S0 (hi+lo) -> Oacc, scaled by lamb
        floatx4 oacc0 = {}, oacc1 = {};
        {
#pragma unroll
            for (int k0 = 0; k0 < 8; ++k0) {
                short8_t bhi, blo;
#pragma unroll
                for (int j = 0; j < 8; ++j) {
                    float sv = S[k0 * 8 + j];
                    unsigned short hh = f2b(sv);
                    bhi[j] = (short)hh;
                    blo[j] = (short)f2b(sv - b2f(hh));
                }
                short8_t a0 = *(const short8_t*)&KQ[vl][k0 * 32 + hq * 8];
                short8_t a1 = *(const short8_t*)&KQ[16 + vl][k0 * 32 + hq * 8];
                oacc0 = __builtin_amdgcn_mfma_f32_16x16x32_bf16(a0, bhi, oacc0, 0, 0, 0);
                oacc0 = __builtin_amdgcn_mfma_f32_16x16x32_bf16(a0, blo, oacc0, 0, 0, 0);
                oacc1 = __builtin_amdgcn_mfma_f32_16x16x32_bf16(a1, bhi, oacc1, 0, 0, 0);
                oacc1 = __builtin_amdgcn_mfma_f32_16x16x32_bf16(a1, blo, oacc1, 0, 0, 0);
            }
#pragma unroll
            for (int r = 0; r < 4; ++r) {
                oacc0[r] *= lamb[4 * hq + r];
                oacc1[r] *= lamb[16 + 4 * hq + r];
            }
        }
        // ---- ph6: solve (I+A) u = b, per wave (its 16 v-cols)
        float u[32];
#pragma unroll
        for (int r = 0; r < 16; ++r) {
            u[r] = Rs[w][r][vl];
            u[16 + r] = 0.f;
        }
#pragma unroll
        for (int r = 1; r < 16; ++r) {
            float a = 0.f;
#pragma unroll
            for (int ll = 0; ll < 16; ++ll)
                if (ll < r) a += Adiag[0][r][ll] * u[ll];
            u[r] -= a;
        }
        {   // R1 = b1 - A_10 u0  (u[16..31]=0 so A_11-strict contributes 0)
            short8_t af = *(const short8_t*)&Ab[16 + vl][hq * 8];
            short8_t bu;
#pragma unroll
            for (int j = 0; j < 8; ++j) {
                float uv = (hq == 0) ? u[j] : (hq == 1) ? u[8 + j] : (hq == 2) ? u[16 + j] : u[24 + j];
                bu[j] = (short)f2b(uv);
            }
            floatx4 racc = {};
            racc = __builtin_amdgcn_mfma_f32_16x16x32_bf16(af, bu, racc, 0, 0, 0);
#pragma unroll
            for (int r = 0; r < 4; ++r)
                Rs[w][16 + 4 * hq + r][vl] = Rs[w][16 + 4 * hq + r][vl] - racc[r];
        }
#pragma unroll
        for (int r = 0; r < 16; ++r) u[16 + r] = Rs[w][16 + r][vl];
#pragma unroll
        for (int r = 1; r < 16; ++r) {
            float a = 0.f;
#pragma unroll
            for (int ll = 0; ll < 16; ++ll)
                if (ll < r) a += Adiag[1][r][ll] * u[16 + ll];
            u[16 + r] -= a;
        }
        // ---- ph7: u -> bf16 frag; M5 = P U into Oacc; store O
        short8_t ub;
#pragma unroll
        for (int j = 0; j < 8; ++j) {
            float uv = (hq == 0) ? u[j] : (hq == 1) ? u[8 + j] : (hq == 2) ? u[16 + j] : u[24 + j];
            ub[j] = (short)f2b(uv);
        }
        {
            short8_t p0 = *(const short8_t*)&Pt[vl][hq * 8];
            short8_t p1 = *(const short8_t*)&Pt[16 + vl][hq * 8];
            oacc0 = __builtin_amdgcn_mfma_f32_16x16x32_bf16(p0, ub, oacc0, 0, 0, 0);
            oacc1 = __builtin_amdgcn_mfma_f32_16x16x32_bf16(p1, ub, oacc1, 0, 0, 0);
        }
#pragma unroll
        for (int mt = 0; mt < 2; ++mt)
#pragma unroll
            for (int r = 0; r < 4; ++r) {
                int ci = mt * 16 + 4 * hq + r;
                float ov = 0.0625f * (mt ? oacc1[r] : oacc0[r]);
                o[((size_t)(b * T_ + t0 + ci) * H_ + h) * DV_ + v0 + w * 16 + vl] = ov;
            }
        // ---- ph8: S = lamC*S + K'^T U (per-mt redistribute via wave scratch)
        {
            float lamC = lamb[31];
#pragma unroll
            for (int mt = 0; mt < 16; ++mt) {
                short8_t af = *(const short8_t*)&KT[mt * 16 + vl][hq * 8];
                floatx4 sacc = {};
                sacc = __builtin_amdgcn_mfma_f32_16x16x32_bf16(af, ub, sacc, 0, 0, 0);
#pragma unroll
                for (int r = 0; r < 4; ++r)
                    Rs[w][4 * hq + r][vl] = sacc[r];
                bool mine = ((hq >> 1) == (mt & 1));
                int m = mt >> 1;
#pragma unroll
                for (int j = 0; j < 8; ++j) {
                    float val = Rs[w][8 * (hq & 1) + j][vl];
                    if (mine) S[m * 8 + j] = lamC * S[m * 8 + j] + val;
                }
            }
        }
        __syncthreads();
    }
}

// ---------------- gated RMSNorm -> bf16 ----------------------------------------
__global__ __launch_bounds__(256) void gnorm_kernel(const float* __restrict__ o,
                                                    const float* __restrict__ gate,
                                                    const float* __restrict__ norm_w,
                                                    __hip_bfloat16* __restrict__ on) {
    int bth = blockIdx.x;
    int tid = threadIdx.x;
    const float* orow = o + (size_t)bth * DV_;
    float v0 = orow[tid], v1 = orow[256 + tid];
    float ss = v0 * v0 + v1 * v1;
    for (int off = 32; off; off >>= 1) ss += __shfl_down(ss, off);
    __shared__ float ws4[4];
    int lane = tid & 63, wv = tid >> 6;
    if (lane == 0) ws4[wv] = ss;
    __syncthreads();
    float tot = ws4[0] + ws4[1] + ws4[2] + ws4[3];
    float r = rsqrtf(tot * (1.f / DV_) + 1e-5f);
    float g0 = gate[(size_t)bth * DV_ + tid];
    float g1 = gate[(size_t)bth * DV_ + 256 + tid];
    on[(size_t)bth * DV_ + tid] = __float2bfloat16(v0 * r * norm_w[tid] * (g0 / (1.f + expf(-g0))));
    on[(size_t)bth * DV_ + 256 + tid] = __float2bfloat16(v1 * r * norm_w[256 + tid] * (g1 / (1.f + expf(-g1))));
}

extern "C" void kernel_launch(void* const* d_in, const int* in_sizes, int n_in,
                              void* d_out, int out_size, void* d_ws, size_t ws_size,
                              hipStream_t stream) {
    const float* x = (const float*)d_in[0];
    const float* Wq = (const float*)d_in[1];
    const float* Wk = (const float*)d_in[2];
    const float* Wv = (const float*)d_in[3];
    const float* cqw = (const float*)d_in[4];
    const float* ckw = (const float*)d_in[5];
    const float* cvw = (const float*)d_in[6];
    const float* Wb = (const float*)d_in[7];
    const float* Wa = (const float*)d_in[8];
    const float* A_log = (const float*)d_in[9];
    const float* dt_bias = (const float*)d_in[10];
    const float* Wg = (const float*)d_in[11];
    const float* norm_w = (const float*)d_in[12];
    const float* Wo = (const float*)d_in[13];
    float* out = (float*)d_out;

    float* ws = (float*)d_ws;
    const size_t M1 = (size_t)1024 * 1024;
    float* qraw = ws;                 // [0, 4M)
    float* kraw = ws + 4 * M1;        // [4, 8M)
    float* vraw = ws + 8 * M1;        // [8, 16M)
    float* graw = ws + 8 * M1;        // reuse after convv
    float* o = ws;                    // reuse after convs
    __hip_bfloat16* qn = (__hip_bfloat16*)(ws + 16 * M1);
    __hip_bfloat16* kn = (__hip_bfloat16*)(ws + 18 * M1);
    __hip_bfloat16* vn = (__hip_bfloat16*)(ws + 20 * M1);
    __hip_bfloat16* onb = (__hip_bfloat16*)(ws + 16 * M1);  // reuse after chunk
    float* g = ws + 24 * M1;
    float* beta = g + (size_t)B_ * T_ * H_;
    unsigned short* xb = (unsigned short*)(ws + 25 * M1);
    unsigned short* WqT = (unsigned short*)(ws + 27 * M1);
    unsigned short* WkT = (unsigned short*)(ws + 27 * M1 + M1 / 2);
    unsigned short* WvT = (unsigned short*)(ws + 28 * M1);
    unsigned short* WgT = (unsigned short*)(ws + 29 * M1);
    unsigned short* WoT = (unsigned short*)(ws + 30 * M1);

    dim3 blk(256);
    tob16_kernel<<<4096, blk, 0, stream>>>(x, xb);
    transpose_bf16_kernel<<<dim3(32, 32), blk, 0, stream>>>(Wq, WqT, 1024, 1024);
    transpose_bf16_kernel<<<dim3(32, 32), blk, 0, stream>>>(Wk, WkT, 1024, 1024);
    transpose_bf16_kernel<<<dim3(64, 32), blk, 0, stream>>>(Wv, WvT, 1024, 2048);
    transpose_bf16_kernel<<<dim3(64, 32), blk, 0, stream>>>(Wg, WgT, 1024, 2048);
    transpose_bf16_kernel<<<dim3(32, 64), blk, 0, stream>>>(Wo, WoT, 2048, 1024);
    gemm_bf16_kernel<<<dim3(8, 32), blk, 0, stream>>>(xb, WqT, qraw, 4096, 1024, 1024);
    gemm_bf16_kernel<<<dim3(8, 32), blk, 0, stream>>>(xb, WkT, kraw, 4096, 1024, 1024);
    gemm_bf16_kernel<<<dim3(16, 32), blk, 0, stream>>>(xb, WvT, vraw, 4096, 2048, 1024);
    betag_kernel<<<4096, blk, 0, stream>>>(x, Wb, Wa, A_log, dt_bias, beta, g);
    convqk_kernel<<<16384, blk, 0, stream>>>(qraw, cqw, qn);
    convqk_kernel<<<16384, blk, 0, stream>>>(kraw, ckw, kn);
    convv_kernel<<<32768, blk, 0, stream>>>(vraw, cvw, vn);
    gemm_bf16_kernel<<<dim3(16, 32), blk, 0, stream>>>(xb, WgT, graw, 4096, 2048, 1024);
    chunk_kernel<<<128, blk, 0, stream>>>(qn, kn, vn, g, beta, o);
    gnorm_kernel<<<16384, blk, 0, stream>>>(o, graw, norm_w, onb);
    gemm_bf16_kernel<<<dim3(8, 32), blk, 0, stream>>>((const unsigned short*)onb, WoT, out, 4096, 1024, 2048);
}

// Round 5
// 765.658 us; speedup vs baseline: 3.1094x; 1.0794x over previous
//
#include <hip/hip_runtime.h>
#include <hip/hip_bf16.h>
#include <math.h>

#define B_ 4
#define T_ 1024
#define D_ 1024
#define H_ 4
#define DK_ 256
#define DV_ 512
#define KC_ 4

typedef __attribute__((ext_vector_type(4))) float floatx4;
typedef __attribute__((ext_vector_type(8))) short short8_t;

__device__ __forceinline__ unsigned short f2b(float f) {
    __hip_bfloat16 h = __float2bfloat16(f);
    return *(unsigned short*)&h;
}
__device__ __forceinline__ float b2f(unsigned short u) {
    unsigned int x = ((unsigned int)u) << 16;
    return *(float*)&x;
}

// ---------------- f32 -> bf16 convert (vectorized, 4 elems/thread) -------------
__global__ __launch_bounds__(256) void tob16_kernel(const float* __restrict__ in,
                                                    unsigned short* __restrict__ out) {
    int i = blockIdx.x * 256 + threadIdx.x;
    float4 f = ((const float4*)in)[i];
    ushort4 u;
    u.x = f2b(f.x); u.y = f2b(f.y); u.z = f2b(f.z); u.w = f2b(f.w);
    ((ushort4*)out)[i] = u;
}

// ---------------- W[K,N] f32 -> Wt[N,K] bf16 (LDS-tiled transpose) -------------
__global__ __launch_bounds__(256) void transpose_bf16_kernel(const float* __restrict__ W,
                                                             unsigned short* __restrict__ Wt,
                                                             int K, int N) {
    __shared__ float Ls[32][33];
    int tx = threadIdx.x & 31, ty = threadIdx.x >> 5;  // ty 0..7
    int k0 = blockIdx.y * 32, n0 = blockIdx.x * 32;
#pragma unroll
    for (int i = 0; i < 4; ++i)
        Ls[ty * 4 + i][tx] = W[(size_t)(k0 + ty * 4 + i) * N + n0 + tx];
    __syncthreads();
#pragma unroll
    for (int i = 0; i < 4; ++i)
        Wt[(size_t)(n0 + ty * 4 + i) * K + k0 + tx] = f2b(Ls[tx][ty * 4 + i]);
}

// ---------------- bf16 MFMA GEMM: C[M,N]f32 = A[M,K]bf16 * Bt[N,K]bf16 ---------
__global__ __launch_bounds__(256) void gemm_bf16_kernel(const unsigned short* __restrict__ A,
                                                        const unsigned short* __restrict__ Bt,
                                                        float* __restrict__ C,
                                                        int M, int N, int K) {
    __shared__ unsigned short As[128 * 40];
    __shared__ unsigned short Bs[128 * 40];
    int tid = threadIdx.x;
    int m0 = blockIdx.y * 128, n0 = blockIdx.x * 128;
    int w = tid >> 6, lane = tid & 63;
    int wm = w >> 1, wn = w & 1;
    floatx4 acc[4][4] = {};

    int c0 = tid, c1 = 256 + tid;
    int r0 = c0 >> 2, col0 = (c0 & 3) * 8;
    int r1 = c1 >> 2, col1 = (c1 & 3) * 8;
    int koff = (lane >> 4) * 8;

    for (int k0 = 0; k0 < K; k0 += 32) {
        short8_t a0 = *(const short8_t*)&A[(size_t)(m0 + r0) * K + k0 + col0];
        short8_t a1 = *(const short8_t*)&A[(size_t)(m0 + r1) * K + k0 + col1];
        short8_t b0 = *(const short8_t*)&Bt[(size_t)(n0 + r0) * K + k0 + col0];
        short8_t b1 = *(const short8_t*)&Bt[(size_t)(n0 + r1) * K + k0 + col1];
        __syncthreads();
        *(short8_t*)&As[r0 * 40 + col0] = a0;
        *(short8_t*)&As[r1 * 40 + col1] = a1;
        *(short8_t*)&Bs[r0 * 40 + col0] = b0;
        *(short8_t*)&Bs[r1 * 40 + col1] = b1;
        __syncthreads();
        short8_t af[4], bf[4];
#pragma unroll
        for (int f = 0; f < 4; ++f) {
            af[f] = *(const short8_t*)&As[(wm * 64 + f * 16 + (lane & 15)) * 40 + koff];
            bf[f] = *(const short8_t*)&Bs[(wn * 64 + f * 16 + (lane & 15)) * 40 + koff];
        }
#pragma unroll
        for (int i = 0; i < 4; ++i)
#pragma unroll
            for (int j = 0; j < 4; ++j)
                acc[i][j] = __builtin_amdgcn_mfma_f32_16x16x32_bf16(af[i], bf[j], acc[i][j], 0, 0, 0);
    }
#pragma unroll
    for (int i = 0; i < 4; ++i) {
        int row = m0 + wm * 64 + i * 16 + (lane >> 4) * 4;
#pragma unroll
        for (int j = 0; j < 4; ++j) {
            int col = n0 + wn * 64 + j * 16 + (lane & 15);
#pragma unroll
            for (int r = 0; r < 4; ++r)
                C[(size_t)(row + r) * N + col] = acc[i][j][r];
        }
    }
}

// ---------------- beta = sigmoid(x@Wb), g = -exp(A_log)*softplus(x@Wa+dt_bias) --
__global__ __launch_bounds__(256) void betag_kernel(const float* __restrict__ x,
                                                    const float* __restrict__ Wb,
                                                    const float* __restrict__ Wa,
                                                    const float* __restrict__ A_log,
                                                    const float* __restrict__ dt_bias,
                                                    float* __restrict__ beta,
                                                    float* __restrict__ g) {
    int row = blockIdx.x;  // b*T + t
    int tid = threadIdx.x;
    const float* xr = x + (size_t)row * D_;
    float pb[H_] = {}, pa[H_] = {};
    for (int j = 0; j < D_ / 256; ++j) {
        int d = j * 256 + tid;
        float xv = xr[d];
#pragma unroll
        for (int h = 0; h < H_; ++h) {
            pb[h] = fmaf(xv, Wb[d * H_ + h], pb[h]);
            pa[h] = fmaf(xv, Wa[d * H_ + h], pa[h]);
        }
    }
#pragma unroll
    for (int h = 0; h < H_; ++h) {
        for (int off = 32; off; off >>= 1) {
            pb[h] += __shfl_down(pb[h], off);
            pa[h] += __shfl_down(pa[h], off);
        }
    }
    __shared__ float ws[4][2][H_];
    int lane = tid & 63, w = tid >> 6;
    if (lane == 0) {
#pragma unroll
        for (int h = 0; h < H_; ++h) {
            ws[w][0][h] = pb[h];
            ws[w][1][h] = pa[h];
        }
    }
    __syncthreads();
    if (tid < H_) {
        float db = ws[0][0][tid] + ws[1][0][tid] + ws[2][0][tid] + ws[3][0][tid];
        float da = ws[0][1][tid] + ws[1][1][tid] + ws[2][1][tid] + ws[3][1][tid];
        beta[(size_t)row * H_ + tid] = 1.f / (1.f + expf(-db));
        float z = da + dt_bias[tid];
        float sp = (z > 20.f) ? z : log1pf(expf(z));
        g[(size_t)row * H_ + tid] = -expf(A_log[tid]) * sp;
    }
}

// ---------------- causal depthwise conv + silu + l2norm (q, k) -> bf16 ---------
__global__ __launch_bounds__(256) void convqk_kernel(const float* __restrict__ raw,
                                                     const float* __restrict__ w,
                                                     __hip_bfloat16* __restrict__ out) {
    int bt_h = blockIdx.x;
    int h = bt_h & (H_ - 1);
    int row = bt_h >> 2;
    int t = row & (T_ - 1);
    int c = threadIdx.x;
    int C = h * DK_ + c;
    float acc = 0.f;
#pragma unroll
    for (int i = 0; i < KC_; ++i) {
        int tt = t - (KC_ - 1) + i;
        if (tt >= 0)
            acc = fmaf(raw[(size_t)(row - (KC_ - 1) + i) * (H_ * DK_) + C], w[C * KC_ + i], acc);
    }
    float s = acc / (1.f + expf(-acc));
    float ss = s * s;
    for (int off = 32; off; off >>= 1) ss += __shfl_down(ss, off);
    __shared__ float ws4[4];
    int lane = threadIdx.x & 63, wv = threadIdx.x >> 6;
    if (lane == 0) ws4[wv] = ss;
    __syncthreads();
    float tot = ws4[0] + ws4[1] + ws4[2] + ws4[3];
    float r = rsqrtf(tot + 1e-6f);
    out[(size_t)bt_h * DK_ + c] = __float2bfloat16(s * r);
}

// ---------------- causal depthwise conv + silu (v) -> bf16 ---------------------
__global__ __launch_bounds__(256) void convv_kernel(const float* __restrict__ raw,
                                                    const float* __restrict__ w,
                                                    __hip_bfloat16* __restrict__ out) {
    size_t idx = (size_t)blockIdx.x * 256 + threadIdx.x;
    int C = idx & (H_ * DV_ - 1);
    int row = (int)(idx >> 11);
    int t = row & (T_ - 1);
    float acc = 0.f;
#pragma unroll
    for (int i = 0; i < KC_; ++i) {
        int tt = t - (KC_ - 1) + i;
        if (tt >= 0)
            acc = fmaf(raw[(size_t)(row - (KC_ - 1) + i) * (H_ * DV_) + C], w[C * KC_ + i], acc);
    }
    out[idx] = __float2bfloat16(acc / (1.f + expf(-acc)));
}

// ---------------- chunk prep (fully parallel over 16 bh x 32 chunks) -----------
// Per (bh,chunk): g-scan; A = bets*D.(KK^T) strict-lower (f32 LDS); solve
// (I+A)W = diag(bets*lamb)K and (I+A)U = diag(bets)V by forward substitution
// (one col/thread for W, two for U); P = D'.(QK^T) masked; KdT = (kdec.K)^T.
__global__ __launch_bounds__(256, 1) void prep_kernel(const unsigned short* __restrict__ qn,
                                                      const unsigned short* __restrict__ kn,
                                                      const unsigned short* __restrict__ vn,
                                                      const float* __restrict__ gl,
                                                      const float* __restrict__ betal,
                                                      unsigned short* __restrict__ Wpg,
                                                      unsigned short* __restrict__ KdTg,
                                                      unsigned short* __restrict__ Pg,
                                                      unsigned short* __restrict__ Ug,
                                                      float* __restrict__ lambg) {
    int blk = blockIdx.x;
    int nc = blk & 31, bh = blk >> 5;
    int b = bh >> 2, h = bh & 3;
    int t0 = nc * 32;
    int tid = threadIdx.x, w = tid >> 6, l = tid & 63;
    int vl = l & 15, hq = l >> 4;
    size_t cb = (size_t)bh * 32 + nc;

    __shared__ __align__(16) unsigned short Kt[32][264];
    __shared__ float Af[32][33];
    __shared__ float gcs[32], lamb[32], bets[32], kdec[32];

    // ph0: gate scan
    if (tid < 32) {
        size_t base = ((size_t)(b * T_ + t0 + tid) * H_ + h);
        float gv = gl[base];
        float bv = betal[base];
        float x = gv;
#pragma unroll
        for (int off = 1; off < 32; off <<= 1) {
            float y = __shfl_up(x, off);
            if (tid >= off) x += y;
        }
        gcs[tid] = x;
        float lm = expf(x);
        lamb[tid] = lm;
        bets[tid] = bv;
        float tot = __shfl(x, 31);
        kdec[tid] = expf(tot - x);
        lambg[cb * 32 + tid] = lm;
    }
    __syncthreads();
    // ph1: stage K
    {
        int r = tid >> 3, c8 = (tid & 7) * 32;
        size_t gbase = ((size_t)(b * T_ + t0 + r) * H_ + h) * DK_;
#pragma unroll
        for (int ii = 0; ii < 4; ++ii)
            *(short8_t*)&Kt[r][c8 + ii * 8] = *(const short8_t*)&kn[gbase + c8 + ii * 8];
    }
    __syncthreads();
    // ph2: A tiles (f32, LDS) + P tiles (bf16, global)
    if (w < 3) {
        int mt = (w == 0) ? 0 : 1;
        int nt = (w == 2) ? 1 : 0;
        floatx4 acc = {};
#pragma unroll
        for (int k0 = 0; k0 < 8; ++k0) {
            short8_t a = *(const short8_t*)&Kt[mt * 16 + vl][k0 * 32 + hq * 8];
            short8_t bb = *(const short8_t*)&Kt[nt * 16 + vl][k0 * 32 + hq * 8];
            acc = __builtin_amdgcn_mfma_f32_16x16x32_bf16(a, bb, acc, 0, 0, 0);
        }
#pragma unroll
        for (int r = 0; r < 4; ++r) {
            int i = mt * 16 + 4 * hq + r, j = nt * 16 + vl;
            Af[i][j] = (j < i) ? bets[i] * expf(gcs[i] - gcs[j]) * acc[r] : 0.f;
        }
        floatx4 accp = {};
#pragma unroll
        for (int k0 = 0; k0 < 8; ++k0) {
            size_t qrow = ((size_t)(b * T_ + t0 + mt * 16 + vl) * H_ + h) * DK_ + k0 * 32 + hq * 8;
            short8_t a = *(const short8_t*)&qn[qrow];
            short8_t bb = *(const short8_t*)&Kt[nt * 16 + vl][k0 * 32 + hq * 8];
            accp = __builtin_amdgcn_mfma_f32_16x16x32_bf16(a, bb, accp, 0, 0, 0);
        }
#pragma unroll
        for (int r = 0; r < 4; ++r) {
            int i = mt * 16 + 4 * hq + r, j = nt * 16 + vl;
            Pg[cb * 1024 + i * 32 + j] = f2b((j <= i) ? expf(gcs[i] - gcs[j]) * accp[r] : 0.f);
        }
    } else {
#pragma unroll
        for (int ii = 0; ii < 4; ++ii)
            Pg[cb * 1024 + (l >> 2) * 32 + 16 + (l & 3) * 4 + ii] = 0;
    }
    // ph2.5: KdT[k][ci] = kdec[ci]*K[ci][k] (coalesced uint stores)
    {
#pragma unroll
        for (int it = 0; it < 16; ++it) {
            int uidx = it * 256 + tid;
            int k = uidx >> 4, cp = (uidx & 15) * 2;
            float kv0 = b2f(Kt[cp][k]) * kdec[cp];
            float kv1 = b2f(Kt[cp + 1][k]) * kdec[cp + 1];
            unsigned int pk = (unsigned int)f2b(kv0) | ((unsigned int)f2b(kv1) << 16);
            ((unsigned int*)KdTg)[cb * 4096 + uidx] = pk;
        }
    }
    __syncthreads();
    // ph3: W-pass forward substitution (col = tid)
    {
        float u[32];
#pragma unroll
        for (int r = 0; r < 32; ++r)
            u[r] = bets[r] * lamb[r] * b2f(Kt[r][tid]);
#pragma unroll
        for (int r = 1; r < 32; ++r) {
            float a = 0.f;
#pragma unroll
            for (int l2 = 0; l2 < 31; ++l2)
                if (l2 < r) a += Af[r][l2] * u[l2];
            u[r] -= a;
        }
#pragma unroll
        for (int r = 0; r < 32; ++r)
            Wpg[cb * 8192 + r * 256 + tid] = f2b(u[r]);
    }
    // ph4: U-pass forward substitution (cols tid, tid+256)
    {
        float ua[32], ub[32];
#pragma unroll
        for (int r = 0; r < 32; ++r) {
            size_t vb = ((size_t)(b * T_ + t0 + r) * H_ + h) * DV_;
            ua[r] = bets[r] * b2f(vn[vb + tid]);
            ub[r] = bets[r] * b2f(vn[vb + 256 + tid]);
        }
#pragma unroll
        for (int r = 1; r < 32; ++r) {
            float a0 = 0.f, a1 = 0.f;
#pragma unroll
            for (int l2 = 0; l2 < 31; ++l2)
                if (l2 < r) {
                    float av = Af[r][l2];
                    a0 = fmaf(av, ua[l2], a0);
                    a1 = fmaf(av, ub[l2], a1);
                }
            ua[r] -= a0;
            ub[r] -= a1;
        }
#pragma unroll
        for (int r = 0; r < 32; ++r) {
            Ug[(cb * 32 + r) * 512 + tid] = f2b(ua[r]);
            Ug[(cb * 32 + r) * 512 + 256 + tid] = f2b(ub[r]);
        }
    }
}

// ---------------- sequential pass: 512 independent single-wave blocks ----------
// block = (bh, vgroup of 16 v-cols); wave owns S_T[16v][256k] in 64 regs/thread.
// Per chunk: u = U - Wp@S; O = lamb.(Q@S) + P@u; S = lamC*S + KdT@u. No barriers.
__global__ __launch_bounds__(64) void seq_kernel(const unsigned short* __restrict__ qn,
                                                 const unsigned short* __restrict__ Wpg,
                                                 const unsigned short* __restrict__ KdTg,
                                                 const unsigned short* __restrict__ Pg,
                                                 const unsigned short* __restrict__ Ug,
                                                 const float* __restrict__ lambg,
                                                 float* __restrict__ o) {
    int blk = blockIdx.x;
    int vg = blk & 31, bh = blk >> 5;
    int b = bh >> 2, h = bh & 3;
    int l = threadIdx.x;
    int vl = l & 15, hq = l >> 4;
    int v0 = vg * 16;

    __shared__ __align__(16) unsigned short Ru[16][40];
    __shared__ float R2[64][17];

    float S[64];
#pragma unroll
    for (int i = 0; i < 64; ++i) S[i] = 0.f;

    for (int nc = 0; nc < 32; ++nc) {
        size_t cb = (size_t)bh * 32 + nc;
        int t0 = nc * 32;
        float lmb0[4], lmb1[4], Ur0[4], Ur1[4];
#pragma unroll
        for (int r = 0; r < 4; ++r) {
            lmb0[r] = lambg[cb * 32 + 4 * hq + r];
            lmb1[r] = lambg[cb * 32 + 16 + 4 * hq + r];
            Ur0[r] = b2f(Ug[(cb * 32 + 4 * hq + r) * 512 + v0 + vl]);
            Ur1[r] = b2f(Ug[(cb * 32 + 16 + 4 * hq + r) * 512 + v0 + vl]);
        }
        float lamC = lambg[cb * 32 + 31];
        short8_t p0 = *(const short8_t*)&Pg[cb * 1024 + vl * 32 + hq * 8];
        short8_t p1 = *(const short8_t*)&Pg[cb * 1024 + (16 + vl) * 32 + hq * 8];

        const unsigned short* Wpc = Wpg + cb * 8192;
        floatx4 ua0 = {}, ua1 = {}, oa0 = {}, oa1 = {};
#pragma unroll
        for (int k0 = 0; k0 < 8; ++k0) {
            short8_t bhi, blo;
#pragma unroll
            for (int j = 0; j < 8; ++j) {
                float sv = S[k0 * 8 + j];
                unsigned short hh = f2b(sv);
                bhi[j] = (short)hh;
                blo[j] = (short)f2b(sv - b2f(hh));
            }
            short8_t wa0 = *(const short8_t*)&Wpc[vl * 256 + k0 * 32 + hq * 8];
            short8_t wa1 = *(const short8_t*)&Wpc[(16 + vl) * 256 + k0 * 32 + hq * 8];
            size_t q0 = ((size_t)(b * T_ + t0 + vl) * H_ + h) * DK_ + k0 * 32 + hq * 8;
            size_t q1 = ((size_t)(b * T_ + t0 + 16 + vl) * H_ + h) * DK_ + k0 * 32 + hq * 8;
            short8_t qa0 = *(const short8_t*)&qn[q0];
            short8_t qa1 = *(const short8_t*)&qn[q1];
            ua0 = __builtin_amdgcn_mfma_f32_16x16x32_bf16(wa0, bhi, ua0, 0, 0, 0);
            ua0 = __builtin_amdgcn_mfma_f32_16x16x32_bf16(wa0, blo, ua0, 0, 0, 0);
            ua1 = __builtin_amdgcn_mfma_f32_16x16x32_bf16(wa1, bhi, ua1, 0, 0, 0);
            ua1 = __builtin_amdgcn_mfma_f32_16x16x32_bf16(wa1, blo, ua1, 0, 0, 0);
            oa0 = __builtin_amdgcn_mfma_f32_16x16x32_bf16(qa0, bhi, oa0, 0, 0, 0);
            oa0 = __builtin_amdgcn_mfma_f32_16x16x32_bf16(qa0, blo, oa0, 0, 0, 0);
            oa1 = __builtin_amdgcn_mfma_f32_16x16x32_bf16(qa1, bhi, oa1, 0, 0, 0);
            oa1 = __builtin_amdgcn_mfma_f32_16x16x32_bf16(qa1, blo, oa1, 0, 0, 0);
        }
        // u = U - Wp@S  -> bf16 -> Ru (wave-local redistribution)
#pragma unroll
        for (int r = 0; r < 4; ++r) {
            Ru[vl][4 * hq + r] = f2b(Ur0[r] - ua0[r]);
            Ru[vl][16 + 4 * hq + r] = f2b(Ur1[r] - ua1[r]);
        }
        short8_t uf = *(const short8_t*)&Ru[vl][8 * hq];
        // O = lamb.(Q@S) + P@u, store
#pragma unroll
        for (int r = 0; r < 4; ++r) {
            oa0[r] *= lmb0[r];
            oa1[r] *= lmb1[r];
        }
        oa0 = __builtin_amdgcn_mfma_f32_16x16x32_bf16(p0, uf, oa0, 0, 0, 0);
        oa1 = __builtin_amdgcn_mfma_f32_16x16x32_bf16(p1, uf, oa1, 0, 0, 0);
#pragma unroll
        for (int r = 0; r < 4; ++r) {
            o[((size_t)(b * T_ + t0 + 4 * hq + r) * H_ + h) * DV_ + v0 + vl] = 0.0625f * oa0[r];
            o[((size_t)(b * T_ + t0 + 16 + 4 * hq + r) * H_ + h) * DV_ + v0 + vl] = 0.0625f * oa1[r];
        }
        // S = lamC*S + KdT@u (4 groups of 64 k-rows via wave-local R2)
        const unsigned short* Kc = KdTg + cb * 8192;
#pragma unroll
        for (int gg = 0; gg < 4; ++gg) {
#pragma unroll
            for (int kt2 = 0; kt2 < 4; ++kt2) {
                int kt = gg * 4 + kt2;
                short8_t ka = *(const short8_t*)&Kc[(kt * 16 + vl) * 32 + hq * 8];
                floatx4 sa = {};
                sa = __builtin_amdgcn_mfma_f32_16x16x32_bf16(ka, uf, sa, 0, 0, 0);
#pragma unroll
                for (int r = 0; r < 4; ++r)
                    R2[kt2 * 16 + 4 * hq + r][vl] = sa[r];
            }
#pragma unroll
            for (int m2 = 0; m2 < 2; ++m2) {
                int m = gg * 2 + m2;
#pragma unroll
                for (int j = 0; j < 8; ++j)
                    S[m * 8 + j] = fmaf(lamC, S[m * 8 + j], R2[m2 * 32 + 8 * hq + j][vl]);
            }
        }
    }
}

// ---------------- gated RMSNorm -> bf16 ----------------------------------------
__global__ __launch_bounds__(256) void gnorm_kernel(const float* __restrict__ o,
                                                    const float* __restrict__ gate,
                                                    const float* __restrict__ norm_w,
                                                    __hip_bfloat16* __restrict__ on) {
    int bth = blockIdx.x;
    int tid = threadIdx.x;
    const float* orow = o + (size_t)bth * DV_;
    float v0 = orow[tid], v1 = orow[256 + tid];
    float ss = v0 * v0 + v1 * v1;
    for (int off = 32; off; off >>= 1) ss += __shfl_down(ss, off);
    __shared__ float ws4[4];
    int lane = tid & 63, wv = tid >> 6;
    if (lane == 0) ws4[wv] = ss;
    __syncthreads();
    float tot = ws4[0] + ws4[1] + ws4[2] + ws4[3];
    float r = rsqrtf(tot * (1.f / DV_) + 1e-5f);
    float g0 = gate[(size_t)bth * DV_ + tid];
    float g1 = gate[(size_t)bth * DV_ + 256 + tid];
    on[(size_t)bth * DV_ + tid] = __float2bfloat16(v0 * r * norm_w[tid] * (g0 / (1.f + expf(-g0))));
    on[(size_t)bth * DV_ + 256 + tid] = __float2bfloat16(v1 * r * norm_w[256 + tid] * (g1 / (1.f + expf(-g1))));
}

extern "C" void kernel_launch(void* const* d_in, const int* in_sizes, int n_in,
                              void* d_out, int out_size, void* d_ws, size_t ws_size,
                              hipStream_t stream) {
    const float* x = (const float*)d_in[0];
    const float* Wq = (const float*)d_in[1];
    const float* Wk = (const float*)d_in[2];
    const float* Wv = (const float*)d_in[3];
    const float* cqw = (const float*)d_in[4];
    const float* ckw = (const float*)d_in[5];
    const float* cvw = (const float*)d_in[6];
    const float* Wb = (const float*)d_in[7];
    const float* Wa = (const float*)d_in[8];
    const float* A_log = (const float*)d_in[9];
    const float* dt_bias = (const float*)d_in[10];
    const float* Wg = (const float*)d_in[11];
    const float* norm_w = (const float*)d_in[12];
    const float* Wo = (const float*)d_in[13];
    float* out = (float*)d_out;

    float* ws = (float*)d_ws;
    const size_t M1 = (size_t)1024 * 1024;
    // region plan (f32 offsets); lifetime-ordered reuse, all <= 31M floats:
    float* qraw = ws;                                        // [0,4M) GEMM out, freed by convqk
    float* kraw = ws + 4 * M1;                               // [4,8M) freed by convqk
    float* vraw = ws + 8 * M1;                               // [8,16M) freed by convv
    float* graw = ws + 8 * M1;                               // [8,16M) gate, live to gnorm
    unsigned short* qn = (unsigned short*)(ws + 16 * M1);    // [16,18M) live to seq
    unsigned short* kn = (unsigned short*)(ws + 18 * M1);    // [18,20M) freed after prep
    unsigned short* vn = (unsigned short*)(ws + 20 * M1);    // [20,24M) freed after prep
    float* g = ws + 24 * M1;                                 // freed after prep
    float* beta = g + 16384;
    unsigned short* Ug = (unsigned short*)ws;                // [0,4M) prep out (bf16), reuse qraw
    float* lambg = ws + 4 * M1;                              // reuse kraw
    unsigned short* Pg = (unsigned short*)(ws + 4 * M1 + 16384);
    float* o = ws + 18 * M1;                                 // [18,26M) seq out (kn/vn/g/xb freed)
    unsigned short* xb = (unsigned short*)(ws + 25 * M1);    // [25,27M) freed after Wg gemm
    unsigned short* WqT = (unsigned short*)(ws + 27 * M1);
    unsigned short* WkT = (unsigned short*)(ws + 27 * M1 + M1 / 2);
    unsigned short* WvT = (unsigned short*)(ws + 28 * M1);
    unsigned short* WgT = (unsigned short*)(ws + 29 * M1);
    unsigned short* WoT = (unsigned short*)(ws + 30 * M1);   // [30,31M) live to end
    unsigned short* Wpg = (unsigned short*)(ws + 26 * M1);   // [26,28M) prep out (xb/WqT/WkT freed)
    unsigned short* KdTg = (unsigned short*)(ws + 28 * M1);  // [28,30M) prep out (WvT/WgT freed)
    __hip_bfloat16* onb = (__hip_bfloat16*)(ws + 16 * M1);   // reuse qn after seq

    dim3 blk(256);
    tob16_kernel<<<4096, blk, 0, stream>>>(x, xb);
    transpose_bf16_kernel<<<dim3(32, 32), blk, 0, stream>>>(Wq, WqT, 1024, 1024);
    transpose_bf16_kernel<<<dim3(32, 32), blk, 0, stream>>>(Wk, WkT, 1024, 1024);
    transpose_bf16_kernel<<<dim3(64, 32), blk, 0, stream>>>(Wv, WvT, 1024, 2048);
    transpose_bf16_kernel<<<dim3(64, 32), blk, 0, stream>>>(Wg, WgT, 1024, 2048);
    transpose_bf16_kernel<<<dim3(32, 64), blk, 0, stream>>>(Wo, WoT, 2048, 1024);
    gemm_bf16_kernel<<<dim3(8, 32), blk, 0, stream>>>(xb, WqT, qraw, 4096, 1024, 1024);
    gemm_bf16_kernel<<<dim3(8, 32), blk, 0, stream>>>(xb, WkT, kraw, 4096, 1024, 1024);
    gemm_bf16_kernel<<<dim3(16, 32), blk, 0, stream>>>(xb, WvT, vraw, 4096, 2048, 1024);
    betag_kernel<<<4096, blk, 0, stream>>>(x, Wb, Wa, A_log, dt_bias, beta, g);
    convqk_kernel<<<16384, blk, 0, stream>>>(qraw, cqw, (__hip_bfloat16*)qn);
    convqk_kernel<<<16384, blk, 0, stream>>>(kraw, ckw, (__hip_bfloat16*)kn);
    convv_kernel<<<32768, blk, 0, stream>>>(vraw, cvw, (__hip_bfloat16*)vn);
    gemm_bf16_kernel<<<dim3(16, 32), blk, 0, stream>>>(xb, WgT, graw, 4096, 2048, 1024);
    prep_kernel<<<512, blk, 0, stream>>>(qn, kn, vn, g, beta, Wpg, KdTg, Pg, Ug, lambg);
    seq_kernel<<<512, dim3(64), 0, stream>>>(qn, Wpg, KdTg, Pg, Ug, lambg, o);
    gnorm_kernel<<<16384, blk, 0, stream>>>(o, graw, norm_w, onb);
    gemm_bf16_kernel<<<dim3(8, 32), blk, 0, stream>>>((const unsigned short*)onb, WoT, out, 4096, 1024, 2048);
}

// Round 6
// 618.115 us; speedup vs baseline: 3.8516x; 1.2387x over previous
//
#include <hip/hip_runtime.h>
#include <hip/hip_bf16.h>
#include <math.h>

#define B_ 4
#define T_ 1024
#define D_ 1024
#define H_ 4
#define DK_ 256
#define DV_ 512
#define KC_ 4

typedef __attribute__((ext_vector_type(4))) float floatx4;
typedef __attribute__((ext_vector_type(8))) short short8_t;

__device__ __forceinline__ unsigned short f2b(float f) {
    __hip_bfloat16 h = __float2bfloat16(f);
    return *(unsigned short*)&h;
}
__device__ __forceinline__ float b2f(unsigned short u) {
    unsigned int x = ((unsigned int)u) << 16;
    return *(float*)&x;
}

// ---------------- f32 -> bf16 convert (vectorized, 4 elems/thread) -------------
__global__ __launch_bounds__(256) void tob16_kernel(const float* __restrict__ in,
                                                    unsigned short* __restrict__ out) {
    int i = blockIdx.x * 256 + threadIdx.x;
    float4 f = ((const float4*)in)[i];
    ushort4 u;
    u.x = f2b(f.x); u.y = f2b(f.y); u.z = f2b(f.z); u.w = f2b(f.w);
    ((ushort4*)out)[i] = u;
}

// ---------------- W[K,N] f32 -> Wt[N,K] bf16 (LDS-tiled transpose) -------------
__global__ __launch_bounds__(256) void transpose_bf16_kernel(const float* __restrict__ W,
                                                             unsigned short* __restrict__ Wt,
                                                             int K, int N) {
    __shared__ float Ls[32][33];
    int tx = threadIdx.x & 31, ty = threadIdx.x >> 5;  // ty 0..7
    int k0 = blockIdx.y * 32, n0 = blockIdx.x * 32;
#pragma unroll
    for (int i = 0; i < 4; ++i)
        Ls[ty * 4 + i][tx] = W[(size_t)(k0 + ty * 4 + i) * N + n0 + tx];
    __syncthreads();
#pragma unroll
    for (int i = 0; i < 4; ++i)
        Wt[(size_t)(n0 + ty * 4 + i) * K + k0 + tx] = f2b(Ls[tx][ty * 4 + i]);
}

// ---------------- bf16 MFMA GEMM: C[M,N]f32 = A[M,K]bf16 * Bt[N,K]bf16 ---------
__global__ __launch_bounds__(256) void gemm_bf16_kernel(const unsigned short* __restrict__ A,
                                                        const unsigned short* __restrict__ Bt,
                                                        float* __restrict__ C,
                                                        int M, int N, int K) {
    __shared__ unsigned short As[128 * 40];
    __shared__ unsigned short Bs[128 * 40];
    int tid = threadIdx.x;
    int m0 = blockIdx.y * 128, n0 = blockIdx.x * 128;
    int w = tid >> 6, lane = tid & 63;
    int wm = w >> 1, wn = w & 1;
    floatx4 acc[4][4] = {};

    int c0 = tid, c1 = 256 + tid;
    int r0 = c0 >> 2, col0 = (c0 & 3) * 8;
    int r1 = c1 >> 2, col1 = (c1 & 3) * 8;
    int koff = (lane >> 4) * 8;

    for (int k0 = 0; k0 < K; k0 += 32) {
        short8_t a0 = *(const short8_t*)&A[(size_t)(m0 + r0) * K + k0 + col0];
        short8_t a1 = *(const short8_t*)&A[(size_t)(m0 + r1) * K + k0 + col1];
        short8_t b0 = *(const short8_t*)&Bt[(size_t)(n0 + r0) * K + k0 + col0];
        short8_t b1 = *(const short8_t*)&Bt[(size_t)(n0 + r1) * K + k0 + col1];
        __syncthreads();
        *(short8_t*)&As[r0 * 40 + col0] = a0;
        *(short8_t*)&As[r1 * 40 + col1] = a1;
        *(short8_t*)&Bs[r0 * 40 + col0] = b0;
        *(short8_t*)&Bs[r1 * 40 + col1] = b1;
        __syncthreads();
        short8_t af[4], bf[4];
#pragma unroll
        for (int f = 0; f < 4; ++f) {
            af[f] = *(const short8_t*)&As[(wm * 64 + f * 16 + (lane & 15)) * 40 + koff];
            bf[f] = *(const short8_t*)&Bs[(wn * 64 + f * 16 + (lane & 15)) * 40 + koff];
        }
#pragma unroll
        for (int i = 0; i < 4; ++i)
#pragma unroll
            for (int j = 0; j < 4; ++j)
                acc[i][j] = __builtin_amdgcn_mfma_f32_16x16x32_bf16(af[i], bf[j], acc[i][j], 0, 0, 0);
    }
#pragma unroll
    for (int i = 0; i < 4; ++i) {
        int row = m0 + wm * 64 + i * 16 + (lane >> 4) * 4;
#pragma unroll
        for (int j = 0; j < 4; ++j) {
            int col = n0 + wn * 64 + j * 16 + (lane & 15);
#pragma unroll
            for (int r = 0; r < 4; ++r)
                C[(size_t)(row + r) * N + col] = acc[i][j][r];
        }
    }
}

// ---------------- beta = sigmoid(x@Wb), g = -exp(A_log)*softplus(x@Wa+dt_bias) --
__global__ __launch_bounds__(256) void betag_kernel(const float* __restrict__ x,
                                                    const float* __restrict__ Wb,
                                                    const float* __restrict__ Wa,
                                                    const float* __restrict__ A_log,
                                                    const float* __restrict__ dt_bias,
                                                    float* __restrict__ beta,
                                                    float* __restrict__ g) {
    int row = blockIdx.x;  // b*T + t
    int tid = threadIdx.x;
    const float* xr = x + (size_t)row * D_;
    float pb[H_] = {}, pa[H_] = {};
    for (int j = 0; j < D_ / 256; ++j) {
        int d = j * 256 + tid;
        float xv = xr[d];
#pragma unroll
        for (int h = 0; h < H_; ++h) {
            pb[h] = fmaf(xv, Wb[d * H_ + h], pb[h]);
            pa[h] = fmaf(xv, Wa[d * H_ + h], pa[h]);
        }
    }
#pragma unroll
    for (int h = 0; h < H_; ++h) {
        for (int off = 32; off; off >>= 1) {
            pb[h] += __shfl_down(pb[h], off);
            pa[h] += __shfl_down(pa[h], off);
        }
    }
    __shared__ float ws[4][2][H_];
    int lane = tid & 63, w = tid >> 6;
    if (lane == 0) {
#pragma unroll
        for (int h = 0; h < H_; ++h) {
            ws[w][0][h] = pb[h];
            ws[w][1][h] = pa[h];
        }
    }
    __syncthreads();
    if (tid < H_) {
        float db = ws[0][0][tid] + ws[1][0][tid] + ws[2][0][tid] + ws[3][0][tid];
        float da = ws[0][1][tid] + ws[1][1][tid] + ws[2][1][tid] + ws[3][1][tid];
        beta[(size_t)row * H_ + tid] = 1.f / (1.f + expf(-db));
        float z = da + dt_bias[tid];
        float sp = (z > 20.f) ? z : log1pf(expf(z));
        g[(size_t)row * H_ + tid] = -expf(A_log[tid]) * sp;
    }
}

// ---------------- causal depthwise conv + silu + l2norm (q, k) -> bf16 ---------
__global__ __launch_bounds__(256) void convqk_kernel(const float* __restrict__ raw,
                                                     const float* __restrict__ w,
                                                     __hip_bfloat16* __restrict__ out) {
    int bt_h = blockIdx.x;
    int h = bt_h & (H_ - 1);
    int row = bt_h >> 2;
    int t = row & (T_ - 1);
    int c = threadIdx.x;
    int C = h * DK_ + c;
    float acc = 0.f;
#pragma unroll
    for (int i = 0; i < KC_; ++i) {
        int tt = t - (KC_ - 1) + i;
        if (tt >= 0)
            acc = fmaf(raw[(size_t)(row - (KC_ - 1) + i) * (H_ * DK_) + C], w[C * KC_ + i], acc);
    }
    float s = acc / (1.f + expf(-acc));
    float ss = s * s;
    for (int off = 32; off; off >>= 1) ss += __shfl_down(ss, off);
    __shared__ float ws4[4];
    int lane = threadIdx.x & 63, wv = threadIdx.x >> 6;
    if (lane == 0) ws4[wv] = ss;
    __syncthreads();
    float tot = ws4[0] + ws4[1] + ws4[2] + ws4[3];
    float r = rsqrtf(tot + 1e-6f);
    out[(size_t)bt_h * DK_ + c] = __float2bfloat16(s * r);
}

// ---------------- causal depthwise conv + silu (v) -> bf16 ---------------------
__global__ __launch_bounds__(256) void convv_kernel(const float* __restrict__ raw,
                                                    const float* __restrict__ w,
                                                    __hip_bfloat16* __restrict__ out) {
    size_t idx = (size_t)blockIdx.x * 256 + threadIdx.x;
    int C = idx & (H_ * DV_ - 1);
    int row = (int)(idx >> 11);
    int t = row & (T_ - 1);
    float acc = 0.f;
#pragma unroll
    for (int i = 0; i < KC_; ++i) {
        int tt = t - (KC_ - 1) + i;
        if (tt >= 0)
            acc = fmaf(raw[(size_t)(row - (KC_ - 1) + i) * (H_ * DV_) + C], w[C * KC_ + i], acc);
    }
    out[idx] = __float2bfloat16(acc / (1.f + expf(-acc)));
}

// ---------------- chunk prep (lean: no solves -> no spills) --------------------
// Per (bh,chunk): g-scan (+ scl stores); A = bets*D.(KK^T) strict-lower -> Afg
// (f32); P = D'.(QK^T) masked -> Pg (bf16); KdT = (kdec.K)^T -> KdTg (bf16).
__global__ __launch_bounds__(256) void prep_kernel(const unsigned short* __restrict__ qn,
                                                   const unsigned short* __restrict__ kn,
                                                   const float* __restrict__ gl,
                                                   const float* __restrict__ betal,
                                                   float* __restrict__ Afg,
                                                   unsigned short* __restrict__ KdTg,
                                                   unsigned short* __restrict__ Pg,
                                                   float* __restrict__ lambg,
                                                   float* __restrict__ scl0,
                                                   float* __restrict__ scl1) {
    int blk = blockIdx.x;
    int nc = blk & 31, bh = blk >> 5;
    int b = bh >> 2, h = bh & 3;
    int t0 = nc * 32;
    int tid = threadIdx.x, w = tid >> 6, l = tid & 63;
    int vl = l & 15, hq = l >> 4;
    size_t cb = (size_t)bh * 32 + nc;

    __shared__ __align__(16) unsigned short Kt[32][264];
    __shared__ float gcs[32], bets[32], kdec[32];

    // ph0: gate scan + per-chunk scalar arrays
    if (tid < 32) {
        size_t base = ((size_t)(b * T_ + t0 + tid) * H_ + h);
        float gv = gl[base];
        float bv = betal[base];
        float x = gv;
#pragma unroll
        for (int off = 1; off < 32; off <<= 1) {
            float y = __shfl_up(x, off);
            if (tid >= off) x += y;
        }
        gcs[tid] = x;
        float lm = expf(x);
        bets[tid] = bv;
        float tot = __shfl(x, 31);
        kdec[tid] = expf(tot - x);
        lambg[cb * 32 + tid] = lm;
        scl0[cb * 32 + tid] = bv * lm;
        scl1[cb * 32 + tid] = bv;
    }
    __syncthreads();
    // ph1: stage K
    {
        int r = tid >> 3, c8 = (tid & 7) * 32;
        size_t gbase = ((size_t)(b * T_ + t0 + r) * H_ + h) * DK_;
#pragma unroll
        for (int ii = 0; ii < 4; ++ii)
            *(short8_t*)&Kt[r][c8 + ii * 8] = *(const short8_t*)&kn[gbase + c8 + ii * 8];
    }
    __syncthreads();
    // ph2: A tiles (f32 -> global) + P tiles (bf16 -> global)
    if (w < 3) {
        int mt = (w == 0) ? 0 : 1;
        int nt = (w == 2) ? 1 : 0;
        floatx4 acc = {};
#pragma unroll
        for (int k0 = 0; k0 < 8; ++k0) {
            short8_t a = *(const short8_t*)&Kt[mt * 16 + vl][k0 * 32 + hq * 8];
            short8_t bb = *(const short8_t*)&Kt[nt * 16 + vl][k0 * 32 + hq * 8];
            acc = __builtin_amdgcn_mfma_f32_16x16x32_bf16(a, bb, acc, 0, 0, 0);
        }
#pragma unroll
        for (int r = 0; r < 4; ++r) {
            int i = mt * 16 + 4 * hq + r, j = nt * 16 + vl;
            Afg[cb * 1024 + i * 32 + j] = (j < i) ? bets[i] * expf(gcs[i] - gcs[j]) * acc[r] : 0.f;
        }
        floatx4 accp = {};
#pragma unroll
        for (int k0 = 0; k0 < 8; ++k0) {
            size_t qrow = ((size_t)(b * T_ + t0 + mt * 16 + vl) * H_ + h) * DK_ + k0 * 32 + hq * 8;
            short8_t a = *(const short8_t*)&qn[qrow];
            short8_t bb = *(const short8_t*)&Kt[nt * 16 + vl][k0 * 32 + hq * 8];
            accp = __builtin_amdgcn_mfma_f32_16x16x32_bf16(a, bb, accp, 0, 0, 0);
        }
#pragma unroll
        for (int r = 0; r < 4; ++r) {
            int i = mt * 16 + 4 * hq + r, j = nt * 16 + vl;
            Pg[cb * 1024 + i * 32 + j] = f2b((j <= i) ? expf(gcs[i] - gcs[j]) * accp[r] : 0.f);
        }
    } else {
#pragma unroll
        for (int ii = 0; ii < 4; ++ii)
            Pg[cb * 1024 + (l >> 2) * 32 + 16 + (l & 3) * 4 + ii] = 0;
    }
    // ph3: KdT[k][ci] = kdec[ci]*K[ci][k] (coalesced uint stores)
    {
#pragma unroll
        for (int it = 0; it < 16; ++it) {
            int uidx = it * 256 + tid;
            int k = uidx >> 4, cp = (uidx & 15) * 2;
            float kv0 = b2f(Kt[cp][k]) * kdec[cp];
            float kv1 = b2f(Kt[cp + 1][k]) * kdec[cp + 1];
            unsigned int pk = (unsigned int)f2b(kv0) | ((unsigned int)f2b(kv1) << 16);
            ((unsigned int*)KdTg)[cb * 4096 + uidx] = pk;
        }
    }
}

// ---------------- triangular solves: (I+A)u = rhs, one column per thread -------
// grid (3, 512): part 0 -> Wp (rhs = scl0.K), parts 1,2 -> U (rhs = scl1.V).
__global__ __launch_bounds__(256) void solve_kernel(const unsigned short* __restrict__ kn,
                                                    const unsigned short* __restrict__ vn,
                                                    const float* __restrict__ Afg,
                                                    const float* __restrict__ scl0,
                                                    const float* __restrict__ scl1,
                                                    unsigned short* __restrict__ Wpg,
                                                    unsigned short* __restrict__ Ug) {
    int part = blockIdx.x;   // 0..2
    int cbi = blockIdx.y;    // 0..511
    int bh = cbi >> 5, nc = cbi & 31;
    int b = bh >> 2, h = bh & 3;
    int t0 = nc * 32;
    int tid = threadIdx.x;

    __shared__ float Af[32][33];
    __shared__ float s0[32];
#pragma unroll
    for (int i = 0; i < 4; ++i) {
        int e = i * 256 + tid;
        Af[e >> 5][e & 31] = Afg[(size_t)cbi * 1024 + e];
    }
    if (tid < 32)
        s0[tid] = (part == 0) ? scl0[(size_t)cbi * 32 + tid] : scl1[(size_t)cbi * 32 + tid];
    __syncthreads();

    float u[32];
    if (part == 0) {
#pragma unroll
        for (int r = 0; r < 32; ++r)
            u[r] = s0[r] * b2f(kn[((size_t)(b * T_ + t0 + r) * H_ + h) * DK_ + tid]);
    } else {
        int col = (part - 1) * 256 + tid;
#pragma unroll
        for (int r = 0; r < 32; ++r)
            u[r] = s0[r] * b2f(vn[((size_t)(b * T_ + t0 + r) * H_ + h) * DV_ + col]);
    }
#pragma unroll
    for (int r = 1; r < 32; ++r) {
        float a = 0.f;
#pragma unroll
        for (int l2 = 0; l2 < r; ++l2)
            a = fmaf(Af[r][l2], u[l2], a);
        u[r] -= a;
    }
    if (part == 0) {
#pragma unroll
        for (int r = 0; r < 32; ++r)
            Wpg[(size_t)cbi * 8192 + r * 256 + tid] = f2b(u[r]);
    } else {
        int col = (part - 1) * 256 + tid;
#pragma unroll
        for (int r = 0; r < 32; ++r)
            Ug[((size_t)cbi * 32 + r) * 512 + col] = f2b(u[r]);
    }
}

// ---------------- sequential pass: 512 blocks x 4 waves (k-split) --------------
// block = (bh, vgroup of 16 v-cols). Wave w owns k-range [w*64, w*64+64):
// S_T[v=vl][k = w*64 + kt*32 + hq*8 + j] in S[kt][j] (16 f32/thread).
// Per chunk: partials Wp@S, Q@S (16 MFMA) -> LDS reduce -> u -> uf broadcast ->
// o = 0.0625*(lamb.QS + P@u) (waves 0,1), S = lamC*S + KdT@u (all waves).
__global__ __launch_bounds__(256) void seq_kernel(const unsigned short* __restrict__ qn,
                                                  const unsigned short* __restrict__ Wpg,
                                                  const unsigned short* __restrict__ KdTg,
                                                  const unsigned short* __restrict__ Pg,
                                                  const unsigned short* __restrict__ Ug,
                                                  const float* __restrict__ lambg,
                                                  float* __restrict__ o) {
    int blk = blockIdx.x;
    int vg = blk & 31, bh = blk >> 5;
    int b = bh >> 2, h = bh & 3;
    int tid = threadIdx.x;
    int w = tid >> 6, l = tid & 63;
    int vl = l & 15, hq = l >> 4;
    int v0 = vg * 16;

    __shared__ float Pu[4][32][17];
    __shared__ float Po[4][32][17];
    __shared__ __align__(16) unsigned short Ru[16][40];
    __shared__ float R2[4][64][17];

    float S[2][8] = {};

    for (int nc = 0; nc < 32; ++nc) {
        size_t cb = (size_t)bh * 32 + nc;
        int t0 = nc * 32;
        // prefetch this chunk's scalars
        int ur_row = 8 * w + 2 * hq;
        float Ur0 = b2f(Ug[(cb * 32 + ur_row) * 512 + v0 + vl]);
        float Ur1 = b2f(Ug[(cb * 32 + ur_row + 1) * 512 + v0 + vl]);
        float lamC = lambg[cb * 32 + 31];
        float lmb[4];
        if (w < 2) {
#pragma unroll
            for (int r = 0; r < 4; ++r)
                lmb[r] = lambg[cb * 32 + 16 * w + 4 * hq + r];
        }
        // ---- phase A: S -> bf16 hi/lo; Wp@S and Q@S partials (16 MFMA)
        short8_t bhi[2], blo[2];
#pragma unroll
        for (int kt = 0; kt < 2; ++kt)
#pragma unroll
            for (int j = 0; j < 8; ++j) {
                float sv = S[kt][j];
                unsigned short hh = f2b(sv);
                bhi[kt][j] = (short)hh;
                blo[kt][j] = (short)f2b(sv - b2f(hh));
            }
        floatx4 ua0 = {}, ua1 = {}, oa0 = {}, oa1 = {};
        const unsigned short* Wpc = Wpg + cb * 8192;
#pragma unroll
        for (int kt = 0; kt < 2; ++kt) {
            int kofs = w * 64 + kt * 32 + hq * 8;
            short8_t wa0 = *(const short8_t*)&Wpc[vl * 256 + kofs];
            short8_t wa1 = *(const short8_t*)&Wpc[(16 + vl) * 256 + kofs];
            short8_t qa0 = *(const short8_t*)&qn[((size_t)(b * T_ + t0 + vl) * H_ + h) * DK_ + kofs];
            short8_t qa1 = *(const short8_t*)&qn[((size_t)(b * T_ + t0 + 16 + vl) * H_ + h) * DK_ + kofs];
            ua0 = __builtin_amdgcn_mfma_f32_16x16x32_bf16(wa0, bhi[kt], ua0, 0, 0, 0);
            ua0 = __builtin_amdgcn_mfma_f32_16x16x32_bf16(wa0, blo[kt], ua0, 0, 0, 0);
            ua1 = __builtin_amdgcn_mfma_f32_16x16x32_bf16(wa1, bhi[kt], ua1, 0, 0, 0);
            ua1 = __builtin_amdgcn_mfma_f32_16x16x32_bf16(wa1, blo[kt], ua1, 0, 0, 0);
            oa0 = __builtin_amdgcn_mfma_f32_16x16x32_bf16(qa0, bhi[kt], oa0, 0, 0, 0);
            oa0 = __builtin_amdgcn_mfma_f32_16x16x32_bf16(qa0, blo[kt], oa0, 0, 0, 0);
            oa1 = __builtin_amdgcn_mfma_f32_16x16x32_bf16(qa1, bhi[kt], oa1, 0, 0, 0);
            oa1 = __builtin_amdgcn_mfma_f32_16x16x32_bf16(qa1, blo[kt], oa1, 0, 0, 0);
        }
#pragma unroll
        for (int r = 0; r < 4; ++r) {
            Pu[w][4 * hq + r][vl] = ua0[r];
            Pu[w][16 + 4 * hq + r][vl] = ua1[r];
            Po[w][4 * hq + r][vl] = oa0[r];
            Po[w][16 + 4 * hq + r][vl] = oa1[r];
        }
        __syncthreads();  // barrier 1
        // ---- phase B: u rows [8w+2hq, +2) col vl; write Ru
#pragma unroll
        for (int j = 0; j < 2; ++j) {
            int r = ur_row + j;
            float s = Pu[0][r][vl] + Pu[1][r][vl] + Pu[2][r][vl] + Pu[3][r][vl];
            Ru[vl][r] = f2b(((j == 0) ? Ur0 : Ur1) - s);
        }
        __syncthreads();  // barrier 2
        // ---- phase C: uf broadcast; o-finish (waves 0,1); S update (all)
        short8_t uf = *(const short8_t*)&Ru[vl][8 * hq];
        if (w < 2) {
            short8_t p = *(const short8_t*)&Pg[cb * 1024 + (w * 16 + vl) * 32 + hq * 8];
            floatx4 pa = {};
            pa = __builtin_amdgcn_mfma_f32_16x16x32_bf16(p, uf, pa, 0, 0, 0);
#pragma unroll
            for (int r = 0; r < 4; ++r) {
                int row = 16 * w + 4 * hq + r;
                float po = Po[0][row][vl] + Po[1][row][vl] + Po[2][row][vl] + Po[3][row][vl];
                o[((size_t)(b * T_ + t0 + row) * H_ + h) * DV_ + v0 + vl] =
                    0.0625f * (lmb[r] * po + pa[r]);
            }
        }
        const unsigned short* Kc = KdTg + cb * 8192;
#pragma unroll
        for (int kt = 0; kt < 4; ++kt) {
            short8_t ka = *(const short8_t*)&Kc[(w * 64 + kt * 16 + vl) * 32 + hq * 8];
            floatx4 sa = {};
            sa = __builtin_amdgcn_mfma_f32_16x16x32_bf16(ka, uf, sa, 0, 0, 0);
#pragma unroll
            for (int r = 0; r < 4; ++r)
                R2[w][kt * 16 + 4 * hq + r][vl] = sa[r];
        }
#pragma unroll
        for (int kt = 0; kt < 2; ++kt)
#pragma unroll
            for (int j = 0; j < 8; ++j)
                S[kt][j] = fmaf(lamC, S[kt][j], R2[w][kt * 32 + hq * 8 + j][vl]);
        __syncthreads();  // barrier 3 (protect Pu/Po/Ru for next chunk)
    }
}

// ---------------- gated RMSNorm -> bf16 ----------------------------------------
__global__ __launch_bounds__(256) void gnorm_kernel(const float* __restrict__ o,
                                                    const float* __restrict__ gate,
                                                    const float* __restrict__ norm_w,
                                                    __hip_bfloat16* __restrict__ on) {
    int bth = blockIdx.x;
    int tid = threadIdx.x;
    const float* orow = o + (size_t)bth * DV_;
    float v0 = orow[tid], v1 = orow[256 + tid];
    float ss = v0 * v0 + v1 * v1;
    for (int off = 32; off; off >>= 1) ss += __shfl_down(ss, off);
    __shared__ float ws4[4];
    int lane = tid & 63, wv = tid >> 6;
    if (lane == 0) ws4[wv] = ss;
    __syncthreads();
    float tot = ws4[0] + ws4[1] + ws4[2] + ws4[3];
    float r = rsqrtf(tot * (1.f / DV_) + 1e-5f);
    float g0 = gate[(size_t)bth * DV_ + tid];
    float g1 = gate[(size_t)bth * DV_ + 256 + tid];
    on[(size_t)bth * DV_ + tid] = __float2bfloat16(v0 * r * norm_w[tid] * (g0 / (1.f + expf(-g0))));
    on[(size_t)bth * DV_ + 256 + tid] = __float2bfloat16(v1 * r * norm_w[256 + tid] * (g1 / (1.f + expf(-g1))));
}

extern "C" void kernel_launch(void* const* d_in, const int* in_sizes, int n_in,
                              void* d_out, int out_size, void* d_ws, size_t ws_size,
                              hipStream_t stream) {
    const float* x = (const float*)d_in[0];
    const float* Wq = (const float*)d_in[1];
    const float* Wk = (const float*)d_in[2];
    const float* Wv = (const float*)d_in[3];
    const float* cqw = (const float*)d_in[4];
    const float* ckw = (const float*)d_in[5];
    const float* cvw = (const float*)d_in[6];
    const float* Wb = (const float*)d_in[7];
    const float* Wa = (const float*)d_in[8];
    const float* A_log = (const float*)d_in[9];
    const float* dt_bias = (const float*)d_in[10];
    const float* Wg = (const float*)d_in[11];
    const float* norm_w = (const float*)d_in[12];
    const float* Wo = (const float*)d_in[13];
    float* out = (float*)d_out;

    float* ws = (float*)d_ws;
    const size_t M1 = (size_t)1024 * 1024;
    // lifetime-ordered regions (f32 offsets):
    float* qraw = ws;                                        // [0,4M) freed by convqk
    float* kraw = ws + 4 * M1;                               // [4,8M) freed by convqk
    float* vraw = ws + 8 * M1;                               // [8,16M) freed by convv
    float* graw = ws + 8 * M1;                               // [8,16M) gate, live to gnorm
    unsigned short* qn = (unsigned short*)(ws + 16 * M1);    // [16,18M) live to seq
    unsigned short* kn = (unsigned short*)(ws + 18 * M1);    // [18,20M) freed after solve
    unsigned short* vn = (unsigned short*)(ws + 20 * M1);    // [20,24M) freed after solve
    float* g = ws + 24 * M1;                                 // freed after prep
    float* beta = g + 16384;
    unsigned short* Ug = (unsigned short*)ws;                // [0,4M) solve out (qraw freed)
    float* lambg = ws + 4 * M1;                              // [4M, 4M+16K)
    unsigned short* Pg = (unsigned short*)(ws + 4 * M1 + 16384);   // 0.25M floats
    float* Afg = ws + 5 * M1;                                // [5M, 5.5M)
    float* scl0 = ws + 5 * M1 + M1 / 2;                      // 16K
    float* scl1 = scl0 + 16384;                              // 16K
    float* o = ws + 18 * M1;                                 // [18,26M) seq out
    unsigned short* xb = (unsigned short*)(ws + 25 * M1);    // [25,27M) freed after Wg gemm
    unsigned short* WqT = (unsigned short*)(ws + 27 * M1);
    unsigned short* WkT = (unsigned short*)(ws + 27 * M1 + M1 / 2);
    unsigned short* WvT = (unsigned short*)(ws + 28 * M1);
    unsigned short* WgT = (unsigned short*)(ws + 29 * M1);
    unsigned short* WoT = (unsigned short*)(ws + 30 * M1);   // [30,31M) live to end
    unsigned short* Wpg = (unsigned short*)(ws + 26 * M1);   // [26,28M) solve out
    unsigned short* KdTg = (unsigned short*)(ws + 28 * M1);  // [28,30M) prep out
    __hip_bfloat16* onb = (__hip_bfloat16*)(ws + 16 * M1);   // reuse qn after seq

    dim3 blk(256);
    tob16_kernel<<<4096, blk, 0, stream>>>(x, xb);
    transpose_bf16_kernel<<<dim3(32, 32), blk, 0, stream>>>(Wq, WqT, 1024, 1024);
    transpose_bf16_kernel<<<dim3(32, 32), blk, 0, stream>>>(Wk, WkT, 1024, 1024);
    transpose_bf16_kernel<<<dim3(64, 32), blk, 0, stream>>>(Wv, WvT, 1024, 2048);
    transpose_bf16_kernel<<<dim3(64, 32), blk, 0, stream>>>(Wg, WgT, 1024, 2048);
    transpose_bf16_kernel<<<dim3(32, 64), blk, 0, stream>>>(Wo, WoT, 2048, 1024);
    gemm_bf16_kernel<<<dim3(8, 32), blk, 0, stream>>>(xb, WqT, qraw, 4096, 1024, 1024);
    gemm_bf16_kernel<<<dim3(8, 32), blk, 0, stream>>>(xb, WkT, kraw, 4096, 1024, 1024);
    gemm_bf16_kernel<<<dim3(16, 32), blk, 0, stream>>>(xb, WvT, vraw, 4096, 2048, 1024);
    betag_kernel<<<4096, blk, 0, stream>>>(x, Wb, Wa, A_log, dt_bias, beta, g);
    convqk_kernel<<<16384, blk, 0, stream>>>(qraw, cqw, (__hip_bfloat16*)qn);
    convqk_kernel<<<16384, blk, 0, stream>>>(kraw, ckw, (__hip_bfloat16*)kn);
    convv_kernel<<<32768, blk, 0, stream>>>(vraw, cvw, (__hip_bfloat16*)vn);
    gemm_bf16_kernel<<<dim3(16, 32), blk, 0, stream>>>(xb, WgT, graw, 4096, 2048, 1024);
    prep_kernel<<<512, blk, 0, stream>>>(qn, kn, g, beta, Afg, KdTg, Pg, lambg, scl0, scl1);
    solve_kernel<<<dim3(3, 512), blk, 0, stream>>>(kn, vn, Afg, scl0, scl1, Wpg, Ug);
    seq_kernel<<<512, blk, 0, stream>>>(qn, Wpg, KdTg, Pg, Ug, lambg, o);
    gnorm_kernel<<<16384, blk, 0, stream>>>(o, graw, norm_w, onb);
    gemm_bf16_kernel<<<dim3(8, 32), blk, 0, stream>>>((const unsigned short*)onb, WoT, out, 4096, 1024, 2048);
}